// Round 3
// baseline (400.999 us; speedup 1.0000x reference)
//
#include <hip/hip_runtime.h>
#include <math.h>

#define B_ 32
#define N_ 64
#define K_ 128
#define NPAIR (B_*N_*N_)
#define PREP_TOTAL 733184

typedef __attribute__((ext_vector_type(8))) short short8;
typedef __attribute__((ext_vector_type(8))) __bf16 bf16x8;
typedef __attribute__((ext_vector_type(4))) float floatx4;

__device__ __forceinline__ float silu_f(float x) {
    return x / (1.0f + expf(-x));
}

__device__ __forceinline__ short f2bf(float x) {
    union { float f; unsigned u; } v; v.f = x;
    unsigned r = (v.u + 0x7FFFu + ((v.u >> 16) & 1u)) >> 16;
    return (short)r;
}
__device__ __forceinline__ float bf2f(short s) {
    union { unsigned u; float f; } v;
    v.u = ((unsigned)(unsigned short)s) << 16;
    return v.f;
}
__device__ __forceinline__ bf16x8 ld_frag(const short* p) {
    short8 r = *(const short8*)p;
    return __builtin_bit_cast(bf16x8, r);
}

// ---------------------------------------------------------------------------
// Kernel 0: weight prep -> bf16 transposed layouts (B-operand: BT[n][k])
// short offsets:
//   0       r1w1T [64][64]
//   4096    r1w2T [64][64]
//   8192    r2w1T [64][64]
//   12288   r2w2T [64][64]
//   16384   r2w3T [256][64]
//   32768   wT0   [512][704] (zero-pad k>=641)
//   393216  wT1   [512][512]
//   655360  w0T_1 [64][32]  (r1w0^T zero-pad k>=8)
//   657408  w0T_2 [64][32]  (r2w0^T zero-pad k>=8)
//   659456  w3T_1 [384][64] (r1w3^T)
//   684032  lcatT [384][128] ([l0|l1|l2]^T concat along n)
//   733184  end
// ---------------------------------------------------------------------------
__global__ __launch_bounds__(256) void prep_kernel(
    const float* __restrict__ r1w1, const float* __restrict__ r1w2,
    const float* __restrict__ r2w1, const float* __restrict__ r2w2,
    const float* __restrict__ r2w3, const float* __restrict__ mw0,
    const float* __restrict__ mw1,
    const float* __restrict__ r1w0, const float* __restrict__ r2w0,
    const float* __restrict__ r1w3,
    const float* __restrict__ l0, const float* __restrict__ l1,
    const float* __restrict__ l2,
    short* __restrict__ dst)
{
    int idx = blockIdx.x * 256 + threadIdx.x;
    if (idx >= PREP_TOTAL) return;
    short v;
    if (idx < 4096) {
        int h = idx >> 6, k = idx & 63; v = f2bf(r1w1[k*64 + h]);
    } else if (idx < 8192) {
        int i = idx - 4096; int h = i >> 6, k = i & 63; v = f2bf(r1w2[k*64 + h]);
    } else if (idx < 12288) {
        int i = idx - 8192; int h = i >> 6, k = i & 63; v = f2bf(r2w1[k*64 + h]);
    } else if (idx < 16384) {
        int i = idx - 12288; int h = i >> 6, k = i & 63; v = f2bf(r2w2[k*64 + h]);
    } else if (idx < 32768) {
        int i = idx - 16384; int col = i >> 6, h = i & 63; v = f2bf(r2w3[h*256 + col]);
    } else if (idx < 393216) {
        int i = idx - 32768; int n = i / 704, k = i - n*704;
        v = (k < 641) ? f2bf(mw0[(size_t)k*512 + n]) : (short)0;
    } else if (idx < 655360) {
        int i = idx - 393216; int n = i >> 9, k = i & 511;
        v = f2bf(mw1[(size_t)k*512 + n]);
    } else if (idx < 657408) {
        int i = idx - 655360; int h = i >> 5, k = i & 31;
        v = (k < 8) ? f2bf(r1w0[k*64 + h]) : (short)0;
    } else if (idx < 659456) {
        int i = idx - 657408; int h = i >> 5, k = i & 31;
        v = (k < 8) ? f2bf(r2w0[k*64 + h]) : (short)0;
    } else if (idx < 684032) {
        int i = idx - 659456; int col = i >> 6, h = i & 63;
        v = f2bf(r1w3[(size_t)h*384 + col]);
    } else {
        int i = idx - 684032; int n = i >> 7, k = i & 127;
        float src = (n < 128) ? l0[(size_t)k*128 + n]
                  : (n < 256) ? l1[(size_t)k*128 + (n-128)]
                              : l2[(size_t)k*128 + (n-256)];
        v = f2bf(src);
    }
    dst[idx] = v;
}

// ---------------------------------------------------------------------------
// Kernel 1: per-pair geometry -> rad[8], Y1[3], Y2[5], maskf  (fp32)
// ---------------------------------------------------------------------------
__global__ __launch_bounds__(256) void geom_kernel(
    const float* __restrict__ pos, const float* __restrict__ cell,
    float* __restrict__ rad, float* __restrict__ Y1, float* __restrict__ Y2,
    float* __restrict__ maskf)
{
    int p = blockIdx.x * 256 + threadIdx.x;
    if (p >= NPAIR) return;
    int b = p >> 12;
    int ij = p & 4095;
    int i = ij >> 6, j = ij & 63;
    const float* pi = pos + (size_t)(b*N_ + i)*3;
    const float* pj = pos + (size_t)(b*N_ + j)*3;
    float d0 = pi[0]-pj[0], d1 = pi[1]-pj[1], d2 = pi[2]-pj[2];
    d0 -= rintf(d0); d1 -= rintf(d1); d2 -= rintf(d2);
    const float* C = cell + b*9;
    float dc0 = d0*C[0] + d1*C[3] + d2*C[6];
    float dc1 = d0*C[1] + d1*C[4] + d2*C[7];
    float dc2 = d0*C[2] + d1*C[5] + d2*C[8];
    float r2 = fmaxf(dc0*dc0 + dc1*dc1 + dc2*dc2, 1e-12f);
    float r = sqrtf(r2);
    bool m = (r < 5.0f) && (i != j);
    float mf = m ? 1.0f : 0.0f;
    float rs = m ? r : 1.0f;
    float inv_rs = 1.0f / rs;
    float x = dc0*inv_rs*mf, y = dc1*inv_rs*mf, z = dc2*inv_rs*mf;
    float u = r * 0.2f;
    float u2 = u*u, u4 = u2*u2, u5 = u4*u;
    float fc = 1.0f - 21.0f*u5 + 35.0f*u5*u - 15.0f*u5*u2;
    fc = (u < 1.0f) ? fc : 0.0f;
    float pref = 0.6324555320336759f * inv_rs * (fc * mf);
    float w = 0.6283185307179586f * rs;
    #pragma unroll
    for (int n = 1; n <= 8; n++)
        rad[(size_t)p*8 + (n-1)] = pref * sinf((float)n * w);
    const float s3  = 1.7320508075688772f;
    const float s5  = 2.23606797749979f;
    const float s15 = 3.872983346207417f;
    float* y1 = Y1 + (size_t)p*3;
    y1[0] = s3*x; y1[1] = s3*y; y1[2] = s3*z;
    float* y2 = Y2 + (size_t)p*5;
    y2[0] = s15*x*y;
    y2[1] = s15*y*z;
    y2[2] = 0.5f*s5*(3.0f*z*z - 1.0f);
    y2[3] = s15*x*z;
    y2[4] = 0.5f*s15*(x*x - y*y);
    maskf[p] = mf;
}

// ---------------------------------------------------------------------------
// Shared MFMA MLP layer: act[64][72]bf16 (LDS) @ WT[64n][64k]bf16 (global)
// -> silu -> dst[64][72]bf16. Wave wv owns rows [16wv,16wv+16).
// ---------------------------------------------------------------------------
__device__ __forceinline__ void mfma_layer(
    const short* __restrict__ src, const short* __restrict__ WT,
    const float* __restrict__ bias, short* __restrict__ dst,
    int wv, int qd, int nn)
{
    floatx4 acc[4];
    #pragma unroll
    for (int tt = 0; tt < 4; tt++) acc[tt] = (floatx4){0.f, 0.f, 0.f, 0.f};
    #pragma unroll
    for (int ks = 0; ks < 64; ks += 32) {
        bf16x8 a = ld_frag(&src[(wv*16 + nn)*72 + ks + qd*8]);
        #pragma unroll
        for (int tt = 0; tt < 4; tt++) {
            bf16x8 b = ld_frag(&WT[(tt*16 + nn)*64 + ks + qd*8]);
            acc[tt] = __builtin_amdgcn_mfma_f32_16x16x32_bf16(a, b, acc[tt], 0, 0, 0);
        }
    }
    #pragma unroll
    for (int tt = 0; tt < 4; tt++) {
        int col = tt*16 + nn;
        float bv = bias[col];
        #pragma unroll
        for (int i = 0; i < 4; i++) {
            int row = wv*16 + qd*4 + i;
            dst[row*72 + col] = f2bf(silu_f(acc[tt][i] + bv));
        }
    }
}

// L0: rad_bf[64][40] (K zero-padded to 32) @ w0T[64][32] -> silu -> act[64][72]
__device__ __forceinline__ void mfma_layer0(
    const short* __restrict__ rad_bf, const short* __restrict__ w0T,
    const float* __restrict__ b0, short* __restrict__ dst,
    int wv, int qd, int nn)
{
    floatx4 acc[4];
    #pragma unroll
    for (int tt = 0; tt < 4; tt++) acc[tt] = (floatx4){0.f, 0.f, 0.f, 0.f};
    bf16x8 a = ld_frag(&rad_bf[(wv*16 + nn)*40 + qd*8]);
    #pragma unroll
    for (int tt = 0; tt < 4; tt++) {
        bf16x8 b = ld_frag(&w0T[(tt*16 + nn)*32 + qd*8]);
        acc[tt] = __builtin_amdgcn_mfma_f32_16x16x32_bf16(a, b, acc[tt], 0, 0, 0);
    }
    #pragma unroll
    for (int tt = 0; tt < 4; tt++) {
        int col = tt*16 + nn;
        float bv = b0[col];
        #pragma unroll
        for (int i = 0; i < 4; i++) {
            int row = wv*16 + qd*4 + i;
            dst[row*72 + col] = f2bf(silu_f(acc[tt][i] + bv));
        }
    }
}

// ---------------------------------------------------------------------------
// Kernel 2: radial MLP (3 layers) for one node's 64 pairs per block.
// TR=1: write hc TRANSPOSED to global: hc[node][h][j]  (for back1's G GEMM)
// TR=0: write hc normal: hc[node][j][h]                (for back2's we2 GEMM)
// ---------------------------------------------------------------------------
template<int TR>
__global__ __launch_bounds__(256) void mlp_kernel(
    const float* __restrict__ rad,
    const short* __restrict__ w0T, const float* __restrict__ b0,
    const short* __restrict__ w1T, const float* __restrict__ b1,
    const short* __restrict__ w2T, const float* __restrict__ b2,
    short* __restrict__ hcOut)
{
    __shared__ __align__(16) short rad_bf[2560];  // [64][40]
    __shared__ __align__(16) short actA[64*72];
    __shared__ __align__(16) short actB[64*72];
    int t = threadIdx.x;
    int wv = t >> 6, lane = t & 63, qd = lane >> 4, nn = lane & 15;
    int node = blockIdx.x;
    size_t pbase = (size_t)node * 64;

    for (int idx = t; idx < 2048; idx += 256) {
        int j = idx >> 5, k = idx & 31;
        rad_bf[j*40 + k] = (k < 8) ? f2bf(rad[pbase*8 + j*8 + k]) : (short)0;
    }
    __syncthreads();
    mfma_layer0(rad_bf, w0T, b0, actA, wv, qd, nn);
    __syncthreads();
    mfma_layer(actA, w1T, b1, actB, wv, qd, nn);
    __syncthreads();

    // final layer -> global
    floatx4 acc[4];
    #pragma unroll
    for (int tt = 0; tt < 4; tt++) acc[tt] = (floatx4){0.f, 0.f, 0.f, 0.f};
    #pragma unroll
    for (int ks = 0; ks < 64; ks += 32) {
        bf16x8 a = ld_frag(&actB[(wv*16 + nn)*72 + ks + qd*8]);
        #pragma unroll
        for (int tt = 0; tt < 4; tt++) {
            bf16x8 b = ld_frag(&w2T[(tt*16 + nn)*64 + ks + qd*8]);
            acc[tt] = __builtin_amdgcn_mfma_f32_16x16x32_bf16(a, b, acc[tt], 0, 0, 0);
        }
    }
    #pragma unroll
    for (int tt = 0; tt < 4; tt++) {
        int col = tt*16 + nn;
        float bv = b2[col];
        if (TR) {
            short4 v;
            v.x = f2bf(silu_f(acc[tt][0] + bv));
            v.y = f2bf(silu_f(acc[tt][1] + bv));
            v.z = f2bf(silu_f(acc[tt][2] + bv));
            v.w = f2bf(silu_f(acc[tt][3] + bv));
            *(short4*)&hcOut[(size_t)node*4096 + col*64 + wv*16 + qd*4] = v;
        } else {
            #pragma unroll
            for (int i = 0; i < 4; i++) {
                int row = wv*16 + qd*4 + i;
                hcOut[(size_t)node*4096 + row*64 + col] = f2bf(silu_f(acc[tt][i] + bv));
            }
        }
    }
}

// ---------------------------------------------------------------------------
// Kernel 3 (back1): one WAVE per node, zero __syncthreads.
// G = Ym @ hcT; msg = (G@w3 + SY*b3)*wemb/16; q; A2; P = A2@lcatT;
// s1/v1/h1/feats out.  Per-wave LDS region; B-operands direct from global.
// ---------------------------------------------------------------------------
#define W1_SIZE 6816   // shorts per wave
__global__ __launch_bounds__(256) void back1_kernel(
    const float* __restrict__ Y1g, const float* __restrict__ Y2g,
    const float* __restrict__ maskg, const float* __restrict__ wemb,
    const short* __restrict__ hcT,
    const short* __restrict__ w3T, const float* __restrict__ b3,
    const short* __restrict__ lcatT, const float* __restrict__ timeg,
    float* __restrict__ h1g, float* __restrict__ v1g, short* __restrict__ featsb)
{
    __shared__ __align__(16) short sdata[4*W1_SIZE];   // 54528 B
    int t = threadIdx.x;
    int wv = t >> 6, lane = t & 63, qd = lane >> 4, nn = lane & 15;
    int node = blockIdx.x*4 + wv;
    int b = node >> 6;
    size_t pbase = (size_t)node * 64;
    short* sw  = sdata + wv*W1_SIZE;
    short* Ym  = sw;                     // [16][72] bf16
    short* Gbf = sw + 1152;              // [16][72] bf16
    short* A2  = sw + 2304;              // [16][136] bf16
    float* msg = (float*)(sw + 4480);    // [9][128] f32
    float* SYl = (float*)(sw + 6784);    // [16] f32
    float* Psa = msg;                    // alias (msg dead by P stage)
    float* Psb = msg + 128;

    // ---- Ym (bf16, masked) + SY (f32 exact) ----
    {
        int j = lane;
        float mf = maskg[pbase + j];
        float vals[9];
        vals[0] = mf;
        #pragma unroll
        for (int m = 0; m < 3; m++) vals[1+m] = Y1g[(pbase+j)*3 + m] * mf;
        #pragma unroll
        for (int m = 0; m < 5; m++) vals[4+m] = Y2g[(pbase+j)*5 + m] * mf;
        #pragma unroll
        for (int m = 0; m < 9; m++) Ym[m*72 + j] = f2bf(vals[m]);
        #pragma unroll
        for (int m = 9; m < 16; m++) Ym[m*72 + j] = 0;
        #pragma unroll
        for (int m = 0; m < 9; m++) {
            float s = vals[m];
            #pragma unroll
            for (int off = 32; off > 0; off >>= 1) s += __shfl_xor(s, off);
            if (lane == m) SYl[m] = s;
        }
    }

    // ---- G = Ym @ hcT  (A from LDS, B from global) ----
    {
        bf16x8 ya0 = ld_frag(&Ym[nn*72 + qd*8]);
        bf16x8 ya1 = ld_frag(&Ym[nn*72 + 32 + qd*8]);
        const short* hb = hcT + (size_t)node*4096 + nn*64 + qd*8;
        #pragma unroll
        for (int tn = 0; tn < 4; tn++) {
            floatx4 acc = (floatx4){0.f, 0.f, 0.f, 0.f};
            bf16x8 b0f = ld_frag(hb + tn*1024);
            bf16x8 b1f = ld_frag(hb + tn*1024 + 32);
            acc = __builtin_amdgcn_mfma_f32_16x16x32_bf16(ya0, b0f, acc, 0, 0, 0);
            acc = __builtin_amdgcn_mfma_f32_16x16x32_bf16(ya1, b1f, acc, 0, 0, 0);
            #pragma unroll
            for (int i = 0; i < 4; i++)
                Gbf[(qd*4 + i)*72 + tn*16 + nn] = f2bf(acc[i]);
        }
    }

    // ---- msg: T = G @ w3T (N=384), scale+bias on the 9 live rows ----
    {
        bf16x8 ga0 = ld_frag(&Gbf[nn*72 + qd*8]);
        bf16x8 ga1 = ld_frag(&Gbf[nn*72 + 32 + qd*8]);
        const short* wb = w3T + nn*64 + qd*8;
        #pragma unroll
        for (int g = 0; g < 4; g++) {
            floatx4 acc[6];
            #pragma unroll
            for (int tt = 0; tt < 6; tt++) acc[tt] = (floatx4){0.f, 0.f, 0.f, 0.f};
            #pragma unroll
            for (int tt = 0; tt < 6; tt++) {
                int tn = g*6 + tt;
                bf16x8 b0f = ld_frag(wb + tn*1024);
                bf16x8 b1f = ld_frag(wb + tn*1024 + 32);
                acc[tt] = __builtin_amdgcn_mfma_f32_16x16x32_bf16(ga0, b0f, acc[tt], 0, 0, 0);
                acc[tt] = __builtin_amdgcn_mfma_f32_16x16x32_bf16(ga1, b1f, acc[tt], 0, 0, 0);
            }
            #pragma unroll
            for (int tt = 0; tt < 6; tt++) {
                int col = (g*6 + tt)*16 + nn;
                #pragma unroll
                for (int i = 0; i < 4; i++) {
                    int m = qd*4 + i;
                    if (m < 9) {
                        int c = (m == 0) ? 0 : ((m < 4) ? 1 : 2);
                        int k = col - c*128;
                        if (k >= 0 && k < 128)
                            msg[m*128 + k] = (acc[tt][i] + SYl[m]*b3[col]) * wemb[k] * 0.0625f;
                    }
                }
            }
        }
    }

    // ---- q + A2 (rows: 0=msg0, 1=q, 2..4=msg1..3, 5..15=0) ----
    {
        int c = lane*2;
        float ma[9], mb[9];
        #pragma unroll
        for (int m = 0; m < 9; m++) { ma[m] = msg[m*128 + c]; mb[m] = msg[m*128 + c + 1]; }
        float qa = 0.f, qb = 0.f;
        #pragma unroll
        for (int m = 4; m < 9; m++) { qa += ma[m]*ma[m]; qb += mb[m]*mb[m]; }
        #pragma unroll
        for (int r = 0; r < 16; r++) {
            float va = (r == 0) ? ma[0] : (r == 1) ? qa : (r < 5) ? ma[r-1] : 0.f;
            float vb = (r == 0) ? mb[0] : (r == 1) ? qb : (r < 5) ? mb[r-1] : 0.f;
            *(short2*)&A2[r*136 + c] = make_short2(f2bf(va), f2bf(vb));
        }
    }

    // ---- P = A2 @ lcatT (N=384, K=128); extract s1 parts + v1 ----
    {
        bf16x8 pa[4];
        #pragma unroll
        for (int ksI = 0; ksI < 4; ksI++)
            pa[ksI] = ld_frag(&A2[nn*136 + ksI*32 + qd*8]);
        const short* lb = lcatT + nn*128 + qd*8;
        #pragma unroll
        for (int g = 0; g < 4; g++) {
            floatx4 acc[6];
            #pragma unroll
            for (int tt = 0; tt < 6; tt++) acc[tt] = (floatx4){0.f, 0.f, 0.f, 0.f};
            #pragma unroll
            for (int tt = 0; tt < 6; tt++) {
                int tn = g*6 + tt;
                #pragma unroll
                for (int ksI = 0; ksI < 4; ksI++) {
                    bf16x8 bf = ld_frag(lb + tn*2048 + ksI*32);
                    acc[tt] = __builtin_amdgcn_mfma_f32_16x16x32_bf16(pa[ksI], bf, acc[tt], 0, 0, 0);
                }
            }
            #pragma unroll
            for (int tt = 0; tt < 6; tt++) {
                int n = (g*6 + tt)*16 + nn;
                #pragma unroll
                for (int i = 0; i < 4; i++) {
                    int r = qd*4 + i;
                    float val = acc[tt][i];
                    if (r == 0 && n < 128) Psa[n] = val;
                    else if (r == 1 && n >= 256) Psb[n - 256] = val;
                    else if (r >= 2 && r < 5 && n >= 128 && n < 256) {
                        int m = r - 2, cc = n - 128;
                        v1g[(size_t)node*384 + m*128 + cc] = val;
                        featsb[(size_t)node*704 + 128 + m*128 + cc] = f2bf(val);
                    }
                }
            }
        }
    }

    // ---- finalize: s1, h1, time, pad ----
    {
        int c = lane*2;
        #pragma unroll
        for (int d = 0; d < 2; d++) {
            float s1 = Psa[c+d] + Psb[c+d];
            featsb[(size_t)node*704 + c + d] = f2bf(s1);
            h1g[(size_t)node*128 + c + d] = silu_f(s1);
        }
        if (lane == 0) featsb[(size_t)node*704 + 640] = f2bf(timeg[b]);
        if (lane < 63) featsb[(size_t)node*704 + 641 + lane] = 0;
    }
}

// ---------------------------------------------------------------------------
// Kernel 4 (back2): one WAVE per node, zero __syncthreads.
// we2 = hc2 @ w3T_2 (M=64, N=256); combine with h1/inv; msgab; s2.
// ---------------------------------------------------------------------------
__global__ __launch_bounds__(256) void back2_kernel(
    const float* __restrict__ Y1g, const float* __restrict__ maskg,
    const short* __restrict__ hc2,
    const short* __restrict__ w3T, const float* __restrict__ b3,
    const float* __restrict__ mix2,
    const float* __restrict__ h1g, const float* __restrict__ v1g,
    short* __restrict__ featsb)
{
    __shared__ float sdataf[4*448];
    int t = threadIdx.x;
    int wv = t >> 6, lane = t & 63, qd = lane >> 4, nn = lane & 15;
    int node = blockIdx.x*4 + wv;
    int b = node >> 6;
    size_t pbase = (size_t)node * 64;
    float* fw     = sdataf + wv*448;
    float* mask_s = fw;          // [64]
    float* Y1s    = fw + 64;     // [64][4]
    float* msgab  = fw + 320;    // [128]

    {
        int j = lane;
        mask_s[j] = maskg[pbase + j];
        #pragma unroll
        for (int m = 0; m < 3; m++) Y1s[j*4 + m] = Y1g[(pbase+j)*3 + m];
    }

    float mreg[8];
    #pragma unroll
    for (int cc = 0; cc < 8; cc++) mreg[cc] = 0.f;

    const short* ab = hc2 + (size_t)node*4096 + nn*64 + qd*8;
    const short* wb = w3T + nn*64 + qd*8;
    #pragma unroll
    for (int mt = 0; mt < 4; mt++) {
        bf16x8 a0 = ld_frag(ab + mt*1024);
        bf16x8 a1 = ld_frag(ab + mt*1024 + 32);
        #pragma unroll
        for (int cg = 0; cg < 4; cg++) {
            floatx4 acc[4];
            #pragma unroll
            for (int tt = 0; tt < 4; tt++) acc[tt] = (floatx4){0.f, 0.f, 0.f, 0.f};
            #pragma unroll
            for (int tt = 0; tt < 4; tt++) {
                int ct = cg*4 + tt;
                bf16x8 b0f = ld_frag(wb + ct*1024);
                bf16x8 b1f = ld_frag(wb + ct*1024 + 32);
                acc[tt] = __builtin_amdgcn_mfma_f32_16x16x32_bf16(a0, b0f, acc[tt], 0, 0, 0);
                acc[tt] = __builtin_amdgcn_mfma_f32_16x16x32_bf16(a1, b1f, acc[tt], 0, 0, 0);
            }
            #pragma unroll
            for (int tt = 0; tt < 4; tt++) {
                int ct = cg*4 + tt;
                int col = ct*16 + nn;
                float bias = b3[col];
                int k = col & 127;
                float p = 0.f;
                if (col < 128) {
                    #pragma unroll
                    for (int i = 0; i < 4; i++) {
                        int j = mt*16 + qd*4 + i;
                        float we = (acc[tt][i] + bias) * mask_s[j];
                        p += we * h1g[((size_t)b*64 + j)*128 + k];
                    }
                } else {
                    #pragma unroll
                    for (int i = 0; i < 4; i++) {
                        int j = mt*16 + qd*4 + i;
                        float we = (acc[tt][i] + bias) * mask_s[j];
                        const float* vb2 = &v1g[((size_t)b*64 + j)*384 + k];
                        float inv = Y1s[j*4+0]*vb2[0] + Y1s[j*4+1]*vb2[128] + Y1s[j*4+2]*vb2[256];
                        p += we * inv;
                    }
                }
                p += __shfl_xor(p, 16);
                p += __shfl_xor(p, 32);
                mreg[ct & 7] += p;
            }
        }
    }

    if (qd == 0) {
        #pragma unroll
        for (int cc = 0; cc < 8; cc++) msgab[cc*16 + nn] = mreg[cc];
    }
    // s2 = msgab @ mix2 / 16
    #pragma unroll
    for (int half = 0; half < 2; half++) {
        int c = half*64 + lane;
        float acc = 0.f;
        for (int k = 0; k < 128; k++) acc += msgab[k] * mix2[k*128 + c];
        featsb[(size_t)node*704 + 512 + c] = f2bf(acc * 0.0625f);
    }
}

// ---------------------------------------------------------------------------
// Kernel 5: bf16 MFMA GEMM, C[M][ldo] = relu(A[M][lda] @ WT^T + bias), bf16 out.
// ---------------------------------------------------------------------------
__global__ __launch_bounds__(256) void gemm_mfma_kernel(
    const short* __restrict__ A, int lda,
    const short* __restrict__ BT, int ldb, int K,
    const float* __restrict__ bias, short* __restrict__ Cout, int ldo)
{
    __shared__ short As[64*72];
    __shared__ short Bs[64*72];
    int t = threadIdx.x;
    int wv = t >> 6, lane = t & 63, qd = lane >> 4, nn = lane & 15;
    int m0 = blockIdx.x * 64, n0 = blockIdx.y * 64;
    floatx4 acc[4];
    #pragma unroll
    for (int tt = 0; tt < 4; tt++) acc[tt] = (floatx4){0.f, 0.f, 0.f, 0.f};

    for (int kc = 0; kc < K; kc += 64) {
        for (int s = t; s < 512; s += 256) {
            int j = s >> 3, kk = (s & 7) * 8;
            *(uint4*)&As[j*72 + kk] = *(const uint4*)&A[(size_t)(m0 + j)*lda + kc + kk];
            *(uint4*)&Bs[j*72 + kk] = *(const uint4*)&BT[(size_t)(n0 + j)*ldb + kc + kk];
        }
        __syncthreads();
        #pragma unroll
        for (int ks = 0; ks < 64; ks += 32) {
            bf16x8 a = ld_frag(&As[(wv*16 + nn)*72 + ks + qd*8]);
            #pragma unroll
            for (int tt = 0; tt < 4; tt++) {
                bf16x8 bb = ld_frag(&Bs[(tt*16 + nn)*72 + ks + qd*8]);
                acc[tt] = __builtin_amdgcn_mfma_f32_16x16x32_bf16(a, bb, acc[tt], 0, 0, 0);
            }
        }
        __syncthreads();
    }
    #pragma unroll
    for (int tt = 0; tt < 4; tt++) {
        int n = n0 + tt*16 + nn;
        float bv = bias[n];
        #pragma unroll
        for (int i = 0; i < 4; i++) {
            int m = m0 + wv*16 + qd*4 + i;
            Cout[(size_t)m*ldo + n] = f2bf(fmaxf(acc[tt][i] + bv, 0.f));
        }
    }
}

// ---------------------------------------------------------------------------
// Kernel 6: out[node,3] = H(bf16)[node,512] @ w2[512,3] + b2. One wave/node.
// ---------------------------------------------------------------------------
__global__ __launch_bounds__(64) void final3_kernel(
    const short* __restrict__ H, const float* __restrict__ w2,
    const float* __restrict__ b2, float* __restrict__ out)
{
    int node = blockIdx.x, lane = threadIdx.x;
    float a0 = 0.f, a1 = 0.f, a2 = 0.f;
    #pragma unroll
    for (int r = 0; r < 8; r++) {
        int k = r*64 + lane;
        float h = bf2f(H[(size_t)node*512 + k]);
        a0 += h * w2[k*3 + 0];
        a1 += h * w2[k*3 + 1];
        a2 += h * w2[k*3 + 2];
    }
    #pragma unroll
    for (int off = 32; off > 0; off >>= 1) {
        a0 += __shfl_down(a0, off);
        a1 += __shfl_down(a1, off);
        a2 += __shfl_down(a2, off);
    }
    if (lane == 0) {
        out[(size_t)node*3 + 0] = a0 + b2[0];
        out[(size_t)node*3 + 1] = a1 + b2[1];
        out[(size_t)node*3 + 2] = a2 + b2[2];
    }
}

extern "C" void kernel_launch(void* const* d_in, const int* in_sizes, int n_in,
                              void* d_out, int out_size, void* d_ws, size_t ws_size,
                              hipStream_t stream) {
    const float* pos   = (const float*)d_in[0];
    const float* timeg = (const float*)d_in[1];
    const float* cell  = (const float*)d_in[2];
    const float* wemb  = (const float*)d_in[3];
    const float* r1w0  = (const float*)d_in[4];
    const float* r1b0  = (const float*)d_in[5];
    const float* r1w1  = (const float*)d_in[6];
    const float* r1b1  = (const float*)d_in[7];
    const float* r1w2  = (const float*)d_in[8];
    const float* r1b2  = (const float*)d_in[9];
    const float* r1w3  = (const float*)d_in[10];
    const float* r1b3  = (const float*)d_in[11];
    const float* l0    = (const float*)d_in[12];
    const float* l1    = (const float*)d_in[13];
    const float* l2    = (const float*)d_in[14];
    const float* r2w0  = (const float*)d_in[15];
    const float* r2b0  = (const float*)d_in[16];
    const float* r2w1  = (const float*)d_in[17];
    const float* r2b1  = (const float*)d_in[18];
    const float* r2w2  = (const float*)d_in[19];
    const float* r2b2  = (const float*)d_in[20];
    const float* r2w3  = (const float*)d_in[21];
    const float* r2b3  = (const float*)d_in[22];
    const float* mix2  = (const float*)d_in[23];
    const float* mw0   = (const float*)d_in[24];
    const float* mb0   = (const float*)d_in[25];
    const float* mw1   = (const float*)d_in[26];
    const float* mb1   = (const float*)d_in[27];
    const float* mw2   = (const float*)d_in[28];
    const float* mb2   = (const float*)d_in[29];

    float* ws    = (float*)d_ws;
    float* rad   = ws;                                   // 1,048,576 f
    float* Y1    = rad   + (size_t)NPAIR*8;              //   393,216 f
    float* Y2    = Y1    + (size_t)NPAIR*3;              //   655,360 f
    float* maskf = Y2    + (size_t)NPAIR*5;              //   131,072 f
    float* h1    = maskf + (size_t)NPAIR;                //   262,144 f
    float* v1    = h1    + (size_t)B_*N_*K_;             //   786,432 f
    short* featsb = (short*)(v1 + (size_t)B_*N_*3*K_);   // 1,441,792 sh (2048x704)
    short* prep  = featsb + (size_t)2048*704;            //   733,184 sh
    short* w1T_1 = prep;
    short* w2T_1 = prep + 4096;
    short* w1T_2 = prep + 8192;
    short* w2T_2 = prep + 12288;
    short* w3T_2 = prep + 16384;
    short* wT0   = prep + 32768;     // [512][704]
    short* wT1   = prep + 393216;    // [512][512]
    short* w0T_1 = prep + 655360;    // [64][32]
    short* w0T_2 = prep + 657408;    // [64][32]
    short* w3T_1 = prep + 659456;    // [384][64]
    short* lcatT = prep + 684032;    // [384][128]
    short* hcbuf = prep + PREP_TOTAL; // 2048x64x64 bf16 = 16.78 MB (reused by both passes)
    // final-MLP activations alias dead geometry buffers (sequenced after back2):
    short* h0bb = (short*)rad;       // 2048x512 bf16 = 2 MB <= rad (4 MB)
    short* h1bb = (short*)Y2;        // 2048x512 bf16 = 2 MB <= Y2 (2.6 MB)

    prep_kernel<<<(PREP_TOTAL + 255)/256, 256, 0, stream>>>(
        r1w1, r1w2, r2w1, r2w2, r2w3, mw0, mw1,
        r1w0, r2w0, r1w3, l0, l1, l2, prep);
    geom_kernel<<<NPAIR/256, 256, 0, stream>>>(pos, cell, rad, Y1, Y2, maskf);
    mlp_kernel<1><<<B_*N_, 256, 0, stream>>>(rad, w0T_1, r1b0, w1T_1, r1b1, w2T_1, r1b2, hcbuf);
    back1_kernel<<<B_*N_/4, 256, 0, stream>>>(Y1, Y2, maskf, wemb, hcbuf,
        w3T_1, r1b3, lcatT, timeg, h1, v1, featsb);
    mlp_kernel<0><<<B_*N_, 256, 0, stream>>>(rad, w0T_2, r2b0, w1T_2, r2b1, w2T_2, r2b2, hcbuf);
    back2_kernel<<<B_*N_/4, 256, 0, stream>>>(Y1, maskf, hcbuf,
        w3T_2, r2b3, mix2, h1, v1, featsb);
    dim3 g0(32, 8);
    gemm_mfma_kernel<<<g0, 256, 0, stream>>>(featsb, 704, wT0, 704, 704, mb0, h0bb, 512);
    gemm_mfma_kernel<<<g0, 256, 0, stream>>>(h0bb, 512, wT1, 512, 512, mb1, h1bb, 512);
    final3_kernel<<<B_*N_, 64, 0, stream>>>(h1bb, mw2, mb2, (float*)d_out);
}

// Round 4
// 290.221 us; speedup vs baseline: 1.3817x; 1.3817x over previous
//
#include <hip/hip_runtime.h>
#include <math.h>

#define B_ 32
#define N_ 64
#define K_ 128
#define NPAIR (B_*N_*N_)
#define PREP_TOTAL 733184

typedef __attribute__((ext_vector_type(8))) short short8;
typedef __attribute__((ext_vector_type(8))) __bf16 bf16x8;
typedef __attribute__((ext_vector_type(4))) float floatx4;

__device__ __forceinline__ float silu_f(float x) {
    return x / (1.0f + expf(-x));
}

__device__ __forceinline__ short f2bf(float x) {
    union { float f; unsigned u; } v; v.f = x;
    unsigned r = (v.u + 0x7FFFu + ((v.u >> 16) & 1u)) >> 16;
    return (short)r;
}
__device__ __forceinline__ float bf2f(short s) {
    union { unsigned u; float f; } v;
    v.u = ((unsigned)(unsigned short)s) << 16;
    return v.f;
}
__device__ __forceinline__ bf16x8 ld_frag(const short* p) {
    short8 r = *(const short8*)p;
    return __builtin_bit_cast(bf16x8, r);
}

// ---------------------------------------------------------------------------
// Kernel 0: weight prep -> bf16 transposed layouts (B-operand: BT[n][k])
// short offsets:
//   0       r1w1T [64][64]
//   4096    r1w2T [64][64]
//   8192    r2w1T [64][64]
//   12288   r2w2T [64][64]
//   16384   r2w3T [256][64]
//   32768   wT0   [512][704] (zero-pad k>=641)
//   393216  wT1   [512][512]
//   655360  w0T_1 [64][32]  (r1w0^T zero-pad k>=8)
//   657408  w0T_2 [64][32]  (r2w0^T zero-pad k>=8)
//   659456  w3T_1 [384][64] (r1w3^T)
//   684032  lcatT [384][128] ([l0|l1|l2]^T concat along n)
//   733184  end
// ---------------------------------------------------------------------------
__global__ __launch_bounds__(256) void prep_kernel(
    const float* __restrict__ r1w1, const float* __restrict__ r1w2,
    const float* __restrict__ r2w1, const float* __restrict__ r2w2,
    const float* __restrict__ r2w3, const float* __restrict__ mw0,
    const float* __restrict__ mw1,
    const float* __restrict__ r1w0, const float* __restrict__ r2w0,
    const float* __restrict__ r1w3,
    const float* __restrict__ l0, const float* __restrict__ l1,
    const float* __restrict__ l2,
    short* __restrict__ dst)
{
    int idx = blockIdx.x * 256 + threadIdx.x;
    if (idx >= PREP_TOTAL) return;
    short v;
    if (idx < 4096) {
        int h = idx >> 6, k = idx & 63; v = f2bf(r1w1[k*64 + h]);
    } else if (idx < 8192) {
        int i = idx - 4096; int h = i >> 6, k = i & 63; v = f2bf(r1w2[k*64 + h]);
    } else if (idx < 12288) {
        int i = idx - 8192; int h = i >> 6, k = i & 63; v = f2bf(r2w1[k*64 + h]);
    } else if (idx < 16384) {
        int i = idx - 12288; int h = i >> 6, k = i & 63; v = f2bf(r2w2[k*64 + h]);
    } else if (idx < 32768) {
        int i = idx - 16384; int col = i >> 6, h = i & 63; v = f2bf(r2w3[h*256 + col]);
    } else if (idx < 393216) {
        int i = idx - 32768; int n = i / 704, k = i - n*704;
        v = (k < 641) ? f2bf(mw0[(size_t)k*512 + n]) : (short)0;
    } else if (idx < 655360) {
        int i = idx - 393216; int n = i >> 9, k = i & 511;
        v = f2bf(mw1[(size_t)k*512 + n]);
    } else if (idx < 657408) {
        int i = idx - 655360; int h = i >> 5, k = i & 31;
        v = (k < 8) ? f2bf(r1w0[k*64 + h]) : (short)0;
    } else if (idx < 659456) {
        int i = idx - 657408; int h = i >> 5, k = i & 31;
        v = (k < 8) ? f2bf(r2w0[k*64 + h]) : (short)0;
    } else if (idx < 684032) {
        int i = idx - 659456; int col = i >> 6, h = i & 63;
        v = f2bf(r1w3[(size_t)h*384 + col]);
    } else {
        int i = idx - 684032; int n = i >> 7, k = i & 127;
        float src = (n < 128) ? l0[(size_t)k*128 + n]
                  : (n < 256) ? l1[(size_t)k*128 + (n-128)]
                              : l2[(size_t)k*128 + (n-256)];
        v = f2bf(src);
    }
    dst[idx] = v;
}

// ---------------------------------------------------------------------------
// Kernel 1: per-pair geometry -> rad[8], Y1[3], Y2[5], maskf  (fp32)
// sin(n*w) via Chebyshev recurrence (1 sinf + 1 cosf instead of 8 sinf).
// ---------------------------------------------------------------------------
__global__ __launch_bounds__(256) void geom_kernel(
    const float* __restrict__ pos, const float* __restrict__ cell,
    float* __restrict__ rad, float* __restrict__ Y1, float* __restrict__ Y2,
    float* __restrict__ maskf)
{
    int p = blockIdx.x * 256 + threadIdx.x;
    if (p >= NPAIR) return;
    int b = p >> 12;
    int ij = p & 4095;
    int i = ij >> 6, j = ij & 63;
    const float* pi = pos + (size_t)(b*N_ + i)*3;
    const float* pj = pos + (size_t)(b*N_ + j)*3;
    float d0 = pi[0]-pj[0], d1 = pi[1]-pj[1], d2 = pi[2]-pj[2];
    d0 -= rintf(d0); d1 -= rintf(d1); d2 -= rintf(d2);
    const float* C = cell + b*9;
    float dc0 = d0*C[0] + d1*C[3] + d2*C[6];
    float dc1 = d0*C[1] + d1*C[4] + d2*C[7];
    float dc2 = d0*C[2] + d1*C[5] + d2*C[8];
    float r2 = fmaxf(dc0*dc0 + dc1*dc1 + dc2*dc2, 1e-12f);
    float r = sqrtf(r2);
    bool m = (r < 5.0f) && (i != j);
    float mf = m ? 1.0f : 0.0f;
    float rs = m ? r : 1.0f;
    float inv_rs = 1.0f / rs;
    float x = dc0*inv_rs*mf, y = dc1*inv_rs*mf, z = dc2*inv_rs*mf;
    float u = r * 0.2f;
    float u2 = u*u, u4 = u2*u2, u5 = u4*u;
    float fc = 1.0f - 21.0f*u5 + 35.0f*u5*u - 15.0f*u5*u2;
    fc = (u < 1.0f) ? fc : 0.0f;
    float pref = 0.6324555320336759f * inv_rs * (fc * mf);
    float w = 0.6283185307179586f * rs;
    float sw = sinf(w), cw = cosf(w);
    float twoc = 2.0f * cw;
    float sm = 0.0f, s = sw;
    #pragma unroll
    for (int n = 1; n <= 8; n++) {
        rad[(size_t)p*8 + (n-1)] = pref * s;
        float nx = twoc*s - sm;
        sm = s; s = nx;
    }
    const float s3  = 1.7320508075688772f;
    const float s5  = 2.23606797749979f;
    const float s15 = 3.872983346207417f;
    float* y1 = Y1 + (size_t)p*3;
    y1[0] = s3*x; y1[1] = s3*y; y1[2] = s3*z;
    float* y2 = Y2 + (size_t)p*5;
    y2[0] = s15*x*y;
    y2[1] = s15*y*z;
    y2[2] = 0.5f*s5*(3.0f*z*z - 1.0f);
    y2[3] = s15*x*z;
    y2[4] = 0.5f*s15*(x*x - y*y);
    maskf[p] = mf;
}

// ---------------------------------------------------------------------------
// Shared MFMA MLP layer: act[64][72]bf16 (LDS) @ WT[64n][64k]bf16 (global)
// -> silu -> dst[64][72]bf16. Wave wv owns rows [16wv,16wv+16).
// ---------------------------------------------------------------------------
__device__ __forceinline__ void mfma_layer(
    const short* __restrict__ src, const short* __restrict__ WT,
    const float* __restrict__ bias, short* __restrict__ dst,
    int wv, int qd, int nn)
{
    floatx4 acc[4];
    #pragma unroll
    for (int tt = 0; tt < 4; tt++) acc[tt] = (floatx4){0.f, 0.f, 0.f, 0.f};
    #pragma unroll
    for (int ks = 0; ks < 64; ks += 32) {
        bf16x8 a = ld_frag(&src[(wv*16 + nn)*72 + ks + qd*8]);
        #pragma unroll
        for (int tt = 0; tt < 4; tt++) {
            bf16x8 b = ld_frag(&WT[(tt*16 + nn)*64 + ks + qd*8]);
            acc[tt] = __builtin_amdgcn_mfma_f32_16x16x32_bf16(a, b, acc[tt], 0, 0, 0);
        }
    }
    #pragma unroll
    for (int tt = 0; tt < 4; tt++) {
        int col = tt*16 + nn;
        float bv = bias[col];
        #pragma unroll
        for (int i = 0; i < 4; i++) {
            int row = wv*16 + qd*4 + i;
            dst[row*72 + col] = f2bf(silu_f(acc[tt][i] + bv));
        }
    }
}

// Same but writes dst TRANSPOSED: dstT[col][row] (ld 72)
__device__ __forceinline__ void mfma_layer_T(
    const short* __restrict__ src, const short* __restrict__ WT,
    const float* __restrict__ bias, short* __restrict__ dstT,
    int wv, int qd, int nn)
{
    floatx4 acc[4];
    #pragma unroll
    for (int tt = 0; tt < 4; tt++) acc[tt] = (floatx4){0.f, 0.f, 0.f, 0.f};
    #pragma unroll
    for (int ks = 0; ks < 64; ks += 32) {
        bf16x8 a = ld_frag(&src[(wv*16 + nn)*72 + ks + qd*8]);
        #pragma unroll
        for (int tt = 0; tt < 4; tt++) {
            bf16x8 b = ld_frag(&WT[(tt*16 + nn)*64 + ks + qd*8]);
            acc[tt] = __builtin_amdgcn_mfma_f32_16x16x32_bf16(a, b, acc[tt], 0, 0, 0);
        }
    }
    #pragma unroll
    for (int tt = 0; tt < 4; tt++) {
        int col = tt*16 + nn;
        float bv = bias[col];
        #pragma unroll
        for (int i = 0; i < 4; i++) {
            int row = wv*16 + qd*4 + i;
            dstT[col*72 + row] = f2bf(silu_f(acc[tt][i] + bv));
        }
    }
}

// L0: rad_bf[64][32] (K zero-padded to 32) @ w0T[64][32] -> silu -> act[64][72]
__device__ __forceinline__ void mfma_layer0(
    const short* __restrict__ rad_bf, const short* __restrict__ w0T,
    const float* __restrict__ b0, short* __restrict__ dst,
    int wv, int qd, int nn)
{
    floatx4 acc[4];
    #pragma unroll
    for (int tt = 0; tt < 4; tt++) acc[tt] = (floatx4){0.f, 0.f, 0.f, 0.f};
    bf16x8 a = ld_frag(&rad_bf[(wv*16 + nn)*32 + qd*8]);
    #pragma unroll
    for (int tt = 0; tt < 4; tt++) {
        bf16x8 b = ld_frag(&w0T[(tt*16 + nn)*32 + qd*8]);
        acc[tt] = __builtin_amdgcn_mfma_f32_16x16x32_bf16(a, b, acc[tt], 0, 0, 0);
    }
    #pragma unroll
    for (int tt = 0; tt < 4; tt++) {
        int col = tt*16 + nn;
        float bv = b0[col];
        #pragma unroll
        for (int i = 0; i < 4; i++) {
            int row = wv*16 + qd*4 + i;
            dst[row*72 + col] = f2bf(silu_f(acc[tt][i] + bv));
        }
    }
}

// ---------------------------------------------------------------------------
// Kernel 2 (pass 1): one block per node. All GEMVs via MFMA.
// LDS regions time-multiplexed: total 23040 B -> 7 blocks/CU.
//   R0 [0..9216):      actA / (late) A2 [16][136]
//   R1 [9216..18432):  actB / (late) msg [9][128] f32 + q_s [128] f32 / Psa|Psb
//   R2 [18432..23040): rad_bf [64][32] / (after L0) Ym_bf [16][72] (+SY in pads)
//                      + G_bf [16][72] at +2304
// ---------------------------------------------------------------------------
__global__ __launch_bounds__(256) void pass1_kernel(
    const float* __restrict__ rad, const float* __restrict__ Y1g,
    const float* __restrict__ Y2g, const float* __restrict__ maskg,
    const float* __restrict__ wemb,
    const short* __restrict__ w0T, const float* __restrict__ b0,
    const short* __restrict__ w1T, const float* __restrict__ b1,
    const short* __restrict__ w2T, const float* __restrict__ b2,
    const short* __restrict__ w3T, const float* __restrict__ b3,
    const short* __restrict__ lcatT, const float* __restrict__ timeg,
    float* __restrict__ h1g, float* __restrict__ v1g, short* __restrict__ featsb)
{
    __shared__ __align__(16) char smem[23040];
    short* actA   = (short*)smem;                   // [64][72]
    short* actB   = (short*)(smem + 9216);          // [64][72]
    float* msg    = (float*)(smem + 9216);          // alias actB: [9][128]
    float* q_s    = (float*)(smem + 9216 + 4608);   // [128]
    short* rad_bf = (short*)(smem + 18432);         // [64][32]
    short* Ym_bf  = (short*)(smem + 18432);         // alias: [16][72], SY in col-64 pads
    short* G_bf   = (short*)(smem + 18432 + 2304);  // [16][72]
    short* A2     = (short*)smem;                   // alias actA: [16][136]
    float* Psa    = (float*)(smem + 9216);          // alias msg
    float* Psb    = Psa + 128;

    int t = threadIdx.x;
    int wv = t >> 6, lane = t & 63, qd = lane >> 4, nn = lane & 15;
    int node = blockIdx.x;
    int b = node >> 6;
    size_t pbase = (size_t)node * 64;

    // ---- stage 1: rad -> bf16 [64][32]; t<64 preload Y/mask + SY reduce ----
    for (int idx = t; idx < 2048; idx += 256) {
        int j = idx >> 5, k = idx & 31;
        rad_bf[j*32 + k] = (k < 8) ? f2bf(rad[pbase*8 + j*8 + k]) : (short)0;
    }
    float vals[9];
    float sy9[9];
    if (t < 64) {
        int j = t;
        float mf = maskg[pbase + j];
        vals[0] = mf;
        #pragma unroll
        for (int m = 0; m < 3; m++) vals[1+m] = Y1g[(pbase+j)*3 + m] * mf;
        #pragma unroll
        for (int m = 0; m < 5; m++) vals[4+m] = Y2g[(pbase+j)*5 + m] * mf;
        #pragma unroll
        for (int m = 0; m < 9; m++) {
            float s = vals[m];
            #pragma unroll
            for (int off = 32; off > 0; off >>= 1) s += __shfl_xor(s, off);
            sy9[m] = s;
        }
    }
    __syncthreads();

    // ---- stage 2: L0 (rad_bf -> actA) ----
    mfma_layer0(rad_bf, w0T, b0, actA, wv, qd, nn);
    __syncthreads();

    // ---- stage 3: write Ym/SY into R2 (rad dead); L1 (actA -> actB) ----
    if (t < 64) {
        int j = t;
        #pragma unroll
        for (int m = 0; m < 9; m++) Ym_bf[m*72 + j] = f2bf(vals[m]);
        #pragma unroll
        for (int m = 9; m < 16; m++) Ym_bf[m*72 + j] = 0;
        #pragma unroll
        for (int m = 0; m < 9; m++)
            if (j == m) *(float*)(&Ym_bf[m*72 + 64]) = sy9[m];
    }
    mfma_layer(actA, w1T, b1, actB, wv, qd, nn);
    __syncthreads();

    // ---- stage 4: L2 transposed (actB -> actA = hcT[h][j]) ----
    mfma_layer_T(actB, w2T, b2, actA, wv, qd, nn);
    __syncthreads();

    // ---- stage 5: G[m][h] = sum_j Ym[m][j]*hc[j][h] ----
    {
        floatx4 acc = (floatx4){0.f, 0.f, 0.f, 0.f};
        #pragma unroll
        for (int ks = 0; ks < 64; ks += 32) {
            bf16x8 a = ld_frag(&Ym_bf[nn*72 + ks + qd*8]);
            bf16x8 bb = ld_frag(&actA[(wv*16 + nn)*72 + ks + qd*8]);
            acc = __builtin_amdgcn_mfma_f32_16x16x32_bf16(a, bb, acc, 0, 0, 0);
        }
        #pragma unroll
        for (int i = 0; i < 4; i++)
            G_bf[(qd*4 + i)*72 + wv*16 + nn] = f2bf(acc[i]);
    }
    __syncthreads();

    // ---- stage 6: msg = (G@w3 + SY*b3)*wemb/16  (into R1; actB dead) ----
    {
        floatx4 acc[6];
        #pragma unroll
        for (int tt = 0; tt < 6; tt++) acc[tt] = (floatx4){0.f, 0.f, 0.f, 0.f};
        #pragma unroll
        for (int ks = 0; ks < 64; ks += 32) {
            bf16x8 a = ld_frag(&G_bf[nn*72 + ks + qd*8]);
            #pragma unroll
            for (int tt = 0; tt < 6; tt++) {
                bf16x8 bb = ld_frag(&w3T[((wv*6 + tt)*16 + nn)*64 + ks + qd*8]);
                acc[tt] = __builtin_amdgcn_mfma_f32_16x16x32_bf16(a, bb, acc[tt], 0, 0, 0);
            }
        }
        #pragma unroll
        for (int tt = 0; tt < 6; tt++) {
            int col = (wv*6 + tt)*16 + nn;
            #pragma unroll
            for (int i = 0; i < 4; i++) {
                int m = qd*4 + i;
                if (m < 9) {
                    int c = (m == 0) ? 0 : ((m < 4) ? 1 : 2);
                    int k = col - c*128;
                    if (k >= 0 && k < 128) {
                        float sym = *(const float*)(&Ym_bf[m*72 + 64]);
                        msg[m*128 + k] = (acc[tt][i] + sym*b3[col]) * wemb[k] * 0.0625f;
                    }
                }
            }
        }
    }
    __syncthreads();

    // ---- stage 7: q[k] = sum_m msg2[m][k]^2 ----
    if (t < 128) {
        int k = t;
        float acc = 0.f;
        #pragma unroll
        for (int m = 4; m < 9; m++) { float v = msg[m*128 + k]; acc += v*v; }
        q_s[k] = acc;
    }
    __syncthreads();

    // ---- stage 8: A2 rows: 0=msg0, 1=q, 2..4=msg1..3, 5..15=0 (into R0) ----
    for (int idx = t; idx < 2048; idx += 256) {
        int r = idx >> 7, k = idx & 127;
        float v = (r == 0) ? msg[k]
                : (r == 1) ? q_s[k]
                : (r < 5)  ? msg[(r-1)*128 + k] : 0.f;
        A2[r*136 + k] = f2bf(v);
    }
    __syncthreads();

    // ---- stage 9: P = A2 @ lcatT (N=384, K=128); extract s1 parts + v1 ----
    {
        bf16x8 pa[4];
        #pragma unroll
        for (int ksI = 0; ksI < 4; ksI++)
            pa[ksI] = ld_frag(&A2[nn*136 + ksI*32 + qd*8]);
        floatx4 acc[6];
        #pragma unroll
        for (int tt = 0; tt < 6; tt++) acc[tt] = (floatx4){0.f, 0.f, 0.f, 0.f};
        #pragma unroll
        for (int tt = 0; tt < 6; tt++) {
            int tn = wv*6 + tt;
            #pragma unroll
            for (int ksI = 0; ksI < 4; ksI++) {
                bf16x8 bf = ld_frag(&lcatT[((size_t)(tn*16 + nn))*128 + ksI*32 + qd*8]);
                acc[tt] = __builtin_amdgcn_mfma_f32_16x16x32_bf16(pa[ksI], bf, acc[tt], 0, 0, 0);
            }
        }
        #pragma unroll
        for (int tt = 0; tt < 6; tt++) {
            int n = (wv*6 + tt)*16 + nn;
            #pragma unroll
            for (int i = 0; i < 4; i++) {
                int r = qd*4 + i;
                float val = acc[tt][i];
                if (r == 0 && n < 128) Psa[n] = val;
                else if (r == 1 && n >= 256) Psb[n - 256] = val;
                else if (r >= 2 && r < 5 && n >= 128 && n < 256) {
                    int m = r - 2, cc = n - 128;
                    v1g[(size_t)node*384 + m*128 + cc] = val;
                    featsb[(size_t)node*704 + 128 + m*128 + cc] = f2bf(val);
                }
            }
        }
    }
    __syncthreads();

    // ---- stage 10: finalize s1/h1/time/pad ----
    if (t < 128) {
        float s1 = Psa[t] + Psb[t];
        featsb[(size_t)node*704 + t] = f2bf(s1);
        h1g[(size_t)node*128 + t] = silu_f(s1);
    } else if (t == 128) {
        featsb[(size_t)node*704 + 640] = f2bf(timeg[b]);
    } else if (t > 128 && t < 192) {
        featsb[(size_t)node*704 + 640 + (t - 128)] = 0;   // zero K-pad 641..703
    }
}

// ---------------------------------------------------------------------------
// Kernel 3 (pass 2): L0 MFMA, L1/L2 MFMA, we2 via MFMA, combine, s2.
// LDS 22528 B -> 7 blocks/CU. R2 (rad) reused for mask/Y1s/msgab after L0.
// ---------------------------------------------------------------------------
__global__ __launch_bounds__(256) void pass2_kernel(
    const float* __restrict__ rad, const float* __restrict__ Y1g,
    const float* __restrict__ maskg,
    const short* __restrict__ w0T, const float* __restrict__ b0,
    const short* __restrict__ w1T, const float* __restrict__ b1,
    const short* __restrict__ w2T, const float* __restrict__ b2,
    const short* __restrict__ w3T, const float* __restrict__ b3,
    const float* __restrict__ mix2,
    const float* __restrict__ h1g, const float* __restrict__ v1g,
    short* __restrict__ featsb)
{
    __shared__ __align__(16) char smem[22528];
    short* actA   = (short*)smem;                 // [64][72]
    short* actB   = (short*)(smem + 9216);        // [64][72]
    short* rad_bf = (short*)(smem + 18432);       // [64][32]
    float* aux    = (float*)(smem + 18432);       // alias after L0
    float* mask_s = aux;          // [64]
    float* Y1s    = aux + 64;     // [64][4]
    float* msgab  = aux + 320;    // [128]

    int t = threadIdx.x;
    int wv = t >> 6, lane = t & 63, qd = lane >> 4, nn = lane & 15;
    int node = blockIdx.x;
    int b = node >> 6;
    size_t pbase = (size_t)node * 64;

    // ---- stage 1: rad staging; preload mask/Y1 into regs ----
    for (int idx = t; idx < 2048; idx += 256) {
        int j = idx >> 5, k = idx & 31;
        rad_bf[j*32 + k] = (k < 8) ? f2bf(rad[pbase*8 + j*8 + k]) : (short)0;
    }
    float pmf = 0.f, py0 = 0.f, py1 = 0.f, py2 = 0.f;
    if (t < 64) {
        pmf = maskg[pbase + t];
        py0 = Y1g[(pbase+t)*3 + 0];
        py1 = Y1g[(pbase+t)*3 + 1];
        py2 = Y1g[(pbase+t)*3 + 2];
    }
    __syncthreads();

    // ---- stage 2: L0 ----
    mfma_layer0(rad_bf, w0T, b0, actA, wv, qd, nn);
    __syncthreads();

    // ---- stage 3: write aux (rad dead); L1 ----
    if (t < 64) {
        mask_s[t] = pmf;
        Y1s[t*4 + 0] = py0; Y1s[t*4 + 1] = py1; Y1s[t*4 + 2] = py2;
    }
    if (t < 128) msgab[t] = 0.f;
    mfma_layer(actA, w1T, b1, actB, wv, qd, nn);
    __syncthreads();

    // ---- stage 4: L2 (actB -> actA = hc) ----
    mfma_layer(actB, w2T, b2, actA, wv, qd, nn);
    __syncthreads();

    // ---- stage 5: we2 = hc @ w3 [64x256]; combine with h1/inv; msgab ----
    for (int g = 0; g < 4; g++) {
        floatx4 acc[4];
        #pragma unroll
        for (int tt = 0; tt < 4; tt++) acc[tt] = (floatx4){0.f, 0.f, 0.f, 0.f};
        #pragma unroll
        for (int ks = 0; ks < 64; ks += 32) {
            bf16x8 a = ld_frag(&actA[(wv*16 + nn)*72 + ks + qd*8]);
            #pragma unroll
            for (int tt = 0; tt < 4; tt++) {
                int col0 = g*64 + tt*16;
                bf16x8 bb = ld_frag(&w3T[(col0 + nn)*64 + ks + qd*8]);
                acc[tt] = __builtin_amdgcn_mfma_f32_16x16x32_bf16(a, bb, acc[tt], 0, 0, 0);
            }
        }
        #pragma unroll
        for (int tt = 0; tt < 4; tt++) {
            int col = g*64 + tt*16 + nn;
            float bias = b3[col];
            int k = col & 127;
            float p = 0.f;
            if (col < 128) {
                #pragma unroll
                for (int i = 0; i < 4; i++) {
                    int j = wv*16 + qd*4 + i;
                    float we = (acc[tt][i] + bias) * mask_s[j];
                    p += we * h1g[((size_t)b*64 + j)*128 + k];
                }
            } else {
                #pragma unroll
                for (int i = 0; i < 4; i++) {
                    int j = wv*16 + qd*4 + i;
                    float we = (acc[tt][i] + bias) * mask_s[j];
                    const float* vb = &v1g[((size_t)b*64 + j)*384 + k];
                    float inv = Y1s[j*4+0]*vb[0] + Y1s[j*4+1]*vb[128] + Y1s[j*4+2]*vb[256];
                    p += we * inv;
                }
            }
            p += __shfl_xor(p, 16);
            p += __shfl_xor(p, 32);
            if (qd == 0) atomicAdd(&msgab[k], p);
        }
    }
    __syncthreads();

    // ---- stage 6: s2 = msgab @ mix2 / 16 ----
    if (t < 128) {
        int c = t;
        float acc = 0.f;
        for (int k = 0; k < 128; k++) acc += msgab[k] * mix2[k*128 + c];
        featsb[(size_t)node*704 + 512 + c] = f2bf(acc * 0.0625f);   // s2
    }
}

// ---------------------------------------------------------------------------
// Kernel 4: bf16 MFMA GEMM, C[M][ldo] = relu(A[M][lda] @ WT^T + bias), bf16 out.
// ---------------------------------------------------------------------------
__global__ __launch_bounds__(256) void gemm_mfma_kernel(
    const short* __restrict__ A, int lda,
    const short* __restrict__ BT, int ldb, int K,
    const float* __restrict__ bias, short* __restrict__ Cout, int ldo)
{
    __shared__ short As[64*72];
    __shared__ short Bs[64*72];
    int t = threadIdx.x;
    int wv = t >> 6, lane = t & 63, qd = lane >> 4, nn = lane & 15;
    int m0 = blockIdx.x * 64, n0 = blockIdx.y * 64;
    floatx4 acc[4];
    #pragma unroll
    for (int tt = 0; tt < 4; tt++) acc[tt] = (floatx4){0.f, 0.f, 0.f, 0.f};

    for (int kc = 0; kc < K; kc += 64) {
        for (int s = t; s < 512; s += 256) {
            int j = s >> 3, kk = (s & 7) * 8;
            *(uint4*)&As[j*72 + kk] = *(const uint4*)&A[(size_t)(m0 + j)*lda + kc + kk];
            *(uint4*)&Bs[j*72 + kk] = *(const uint4*)&BT[(size_t)(n0 + j)*ldb + kc + kk];
        }
        __syncthreads();
        #pragma unroll
        for (int ks = 0; ks < 64; ks += 32) {
            bf16x8 a = ld_frag(&As[(wv*16 + nn)*72 + ks + qd*8]);
            #pragma unroll
            for (int tt = 0; tt < 4; tt++) {
                bf16x8 bb = ld_frag(&Bs[(tt*16 + nn)*72 + ks + qd*8]);
                acc[tt] = __builtin_amdgcn_mfma_f32_16x16x32_bf16(a, bb, acc[tt], 0, 0, 0);
            }
        }
        __syncthreads();
    }
    #pragma unroll
    for (int tt = 0; tt < 4; tt++) {
        int n = n0 + tt*16 + nn;
        float bv = bias[n];
        #pragma unroll
        for (int i = 0; i < 4; i++) {
            int m = m0 + wv*16 + qd*4 + i;
            Cout[(size_t)m*ldo + n] = f2bf(fmaxf(acc[tt][i] + bv, 0.f));
        }
    }
}

// ---------------------------------------------------------------------------
// Kernel 5: out[node,3] = H(bf16)[node,512] @ w2[512,3] + b2. One wave/node.
// ---------------------------------------------------------------------------
__global__ __launch_bounds__(64) void final3_kernel(
    const short* __restrict__ H, const float* __restrict__ w2,
    const float* __restrict__ b2, float* __restrict__ out)
{
    int node = blockIdx.x, lane = threadIdx.x;
    float a0 = 0.f, a1 = 0.f, a2 = 0.f;
    #pragma unroll
    for (int r = 0; r < 8; r++) {
        int k = r*64 + lane;
        float h = bf2f(H[(size_t)node*512 + k]);
        a0 += h * w2[k*3 + 0];
        a1 += h * w2[k*3 + 1];
        a2 += h * w2[k*3 + 2];
    }
    #pragma unroll
    for (int off = 32; off > 0; off >>= 1) {
        a0 += __shfl_down(a0, off);
        a1 += __shfl_down(a1, off);
        a2 += __shfl_down(a2, off);
    }
    if (lane == 0) {
        out[(size_t)node*3 + 0] = a0 + b2[0];
        out[(size_t)node*3 + 1] = a1 + b2[1];
        out[(size_t)node*3 + 2] = a2 + b2[2];
    }
}

extern "C" void kernel_launch(void* const* d_in, const int* in_sizes, int n_in,
                              void* d_out, int out_size, void* d_ws, size_t ws_size,
                              hipStream_t stream) {
    const float* pos   = (const float*)d_in[0];
    const float* timeg = (const float*)d_in[1];
    const float* cell  = (const float*)d_in[2];
    const float* wemb  = (const float*)d_in[3];
    const float* r1w0  = (const float*)d_in[4];
    const float* r1b0  = (const float*)d_in[5];
    const float* r1w1  = (const float*)d_in[6];
    const float* r1b1  = (const float*)d_in[7];
    const float* r1w2  = (const float*)d_in[8];
    const float* r1b2  = (const float*)d_in[9];
    const float* r1w3  = (const float*)d_in[10];
    const float* r1b3  = (const float*)d_in[11];
    const float* l0    = (const float*)d_in[12];
    const float* l1    = (const float*)d_in[13];
    const float* l2    = (const float*)d_in[14];
    const float* r2w0  = (const float*)d_in[15];
    const float* r2b0  = (const float*)d_in[16];
    const float* r2w1  = (const float*)d_in[17];
    const float* r2b1  = (const float*)d_in[18];
    const float* r2w2  = (const float*)d_in[19];
    const float* r2b2  = (const float*)d_in[20];
    const float* r2w3  = (const float*)d_in[21];
    const float* r2b3  = (const float*)d_in[22];
    const float* mix2  = (const float*)d_in[23];
    const float* mw0   = (const float*)d_in[24];
    const float* mb0   = (const float*)d_in[25];
    const float* mw1   = (const float*)d_in[26];
    const float* mb1   = (const float*)d_in[27];
    const float* mw2   = (const float*)d_in[28];
    const float* mb2   = (const float*)d_in[29];

    float* ws    = (float*)d_ws;
    float* rad   = ws;                                   // 1,048,576 f
    float* Y1    = rad   + (size_t)NPAIR*8;              //   393,216 f
    float* Y2    = Y1    + (size_t)NPAIR*3;              //   655,360 f
    float* maskf = Y2    + (size_t)NPAIR*5;              //   131,072 f
    float* h1    = maskf + (size_t)NPAIR;                //   262,144 f
    float* v1    = h1    + (size_t)B_*N_*K_;             //   786,432 f
    short* featsb = (short*)(v1 + (size_t)B_*N_*3*K_);   // 1,441,792 sh (2048x704)
    short* prep  = featsb + (size_t)2048*704;            //   733,184 sh
    short* w1T_1 = prep;
    short* w2T_1 = prep + 4096;
    short* w1T_2 = prep + 8192;
    short* w2T_2 = prep + 12288;
    short* w3T_2 = prep + 16384;
    short* wT0   = prep + 32768;     // [512][704]
    short* wT1   = prep + 393216;    // [512][512]
    short* w0T_1 = prep + 655360;    // [64][32]
    short* w0T_2 = prep + 657408;    // [64][32]
    short* w3T_1 = prep + 659456;    // [384][64]
    short* lcatT = prep + 684032;    // [384][128]
    // final-MLP activations alias dead geometry buffers (sequenced after pass2):
    short* h0bb = (short*)rad;       // 2048x512 bf16 = 2 MB <= rad (4 MB)
    short* h1bb = (short*)Y2;        // 2048x512 bf16 = 2 MB <= Y2 (2.6 MB)

    prep_kernel<<<(PREP_TOTAL + 255)/256, 256, 0, stream>>>(
        r1w1, r1w2, r2w1, r2w2, r2w3, mw0, mw1,
        r1w0, r2w0, r1w3, l0, l1, l2, prep);
    geom_kernel<<<NPAIR/256, 256, 0, stream>>>(pos, cell, rad, Y1, Y2, maskf);
    pass1_kernel<<<B_*N_, 256, 0, stream>>>(rad, Y1, Y2, maskf, wemb,
        w0T_1, r1b0, w1T_1, r1b1, w2T_1, r1b2, w3T_1, r1b3, lcatT, timeg,
        h1, v1, featsb);
    pass2_kernel<<<B_*N_, 256, 0, stream>>>(rad, Y1, maskf,
        w0T_2, r2b0, w1T_2, r2b1, w2T_2, r2b2, w3T_2, r2b3, mix2, h1, v1, featsb);
    dim3 g0(32, 8);
    gemm_mfma_kernel<<<g0, 256, 0, stream>>>(featsb, 704, wT0, 704, 704, mb0, h0bb, 512);
    gemm_mfma_kernel<<<g0, 256, 0, stream>>>(h0bb, 512, wT1, 512, 512, mb1, h1bb, 512);
    final3_kernel<<<B_*N_, 64, 0, stream>>>(h1bb, mw2, mb2, (float*)d_out);
}

// Round 5
// 287.468 us; speedup vs baseline: 1.3949x; 1.0096x over previous
//
#include <hip/hip_runtime.h>
#include <math.h>

#define B_ 32
#define N_ 64
#define K_ 128
#define NPAIR (B_*N_*N_)
#define PREP_TOTAL 733184

typedef __attribute__((ext_vector_type(8))) short short8;
typedef __attribute__((ext_vector_type(8))) __bf16 bf16x8;
typedef __attribute__((ext_vector_type(4))) float floatx4;

__device__ __forceinline__ float silu_f(float x) {
    return x / (1.0f + expf(-x));
}

__device__ __forceinline__ short f2bf(float x) {
    union { float f; unsigned u; } v; v.f = x;
    unsigned r = (v.u + 0x7FFFu + ((v.u >> 16) & 1u)) >> 16;
    return (short)r;
}
__device__ __forceinline__ float bf2f(short s) {
    union { unsigned u; float f; } v;
    v.u = ((unsigned)(unsigned short)s) << 16;
    return v.f;
}
__device__ __forceinline__ bf16x8 ld_frag(const short* p) {
    short8 r = *(const short8*)p;
    return __builtin_bit_cast(bf16x8, r);
}

// ---------------------------------------------------------------------------
// Kernel 0: weight prep -> bf16 transposed layouts (B-operand: BT[n][k])
// short offsets:
//   0       r1w1T [64][64]
//   4096    r1w2T [64][64]
//   8192    r2w1T [64][64]
//   12288   r2w2T [64][64]
//   16384   r2w3T [256][64]
//   32768   wT0   [512][704] (zero-pad k>=641)
//   393216  wT1   [512][512]
//   655360  w0T_1 [64][32]  (r1w0^T zero-pad k>=8)
//   657408  w0T_2 [64][32]  (r2w0^T zero-pad k>=8)
//   659456  w3T_1 [384][64] (r1w3^T)
//   684032  lcatT [384][128] ([l0|l1|l2]^T concat along n)
//   733184  end
// ---------------------------------------------------------------------------
__global__ __launch_bounds__(256) void prep_kernel(
    const float* __restrict__ r1w1, const float* __restrict__ r1w2,
    const float* __restrict__ r2w1, const float* __restrict__ r2w2,
    const float* __restrict__ r2w3, const float* __restrict__ mw0,
    const float* __restrict__ mw1,
    const float* __restrict__ r1w0, const float* __restrict__ r2w0,
    const float* __restrict__ r1w3,
    const float* __restrict__ l0, const float* __restrict__ l1,
    const float* __restrict__ l2,
    short* __restrict__ dst)
{
    int idx = blockIdx.x * 256 + threadIdx.x;
    if (idx >= PREP_TOTAL) return;
    short v;
    if (idx < 4096) {
        int h = idx >> 6, k = idx & 63; v = f2bf(r1w1[k*64 + h]);
    } else if (idx < 8192) {
        int i = idx - 4096; int h = i >> 6, k = i & 63; v = f2bf(r1w2[k*64 + h]);
    } else if (idx < 12288) {
        int i = idx - 8192; int h = i >> 6, k = i & 63; v = f2bf(r2w1[k*64 + h]);
    } else if (idx < 16384) {
        int i = idx - 12288; int h = i >> 6, k = i & 63; v = f2bf(r2w2[k*64 + h]);
    } else if (idx < 32768) {
        int i = idx - 16384; int col = i >> 6, h = i & 63; v = f2bf(r2w3[h*256 + col]);
    } else if (idx < 393216) {
        int i = idx - 32768; int n = i / 704, k = i - n*704;
        v = (k < 641) ? f2bf(mw0[(size_t)k*512 + n]) : (short)0;
    } else if (idx < 655360) {
        int i = idx - 393216; int n = i >> 9, k = i & 511;
        v = f2bf(mw1[(size_t)k*512 + n]);
    } else if (idx < 657408) {
        int i = idx - 655360; int h = i >> 5, k = i & 31;
        v = (k < 8) ? f2bf(r1w0[k*64 + h]) : (short)0;
    } else if (idx < 659456) {
        int i = idx - 657408; int h = i >> 5, k = i & 31;
        v = (k < 8) ? f2bf(r2w0[k*64 + h]) : (short)0;
    } else if (idx < 684032) {
        int i = idx - 659456; int col = i >> 6, h = i & 63;
        v = f2bf(r1w3[(size_t)h*384 + col]);
    } else {
        int i = idx - 684032; int n = i >> 7, k = i & 127;
        float src = (n < 128) ? l0[(size_t)k*128 + n]
                  : (n < 256) ? l1[(size_t)k*128 + (n-128)]
                              : l2[(size_t)k*128 + (n-256)];
        v = f2bf(src);
    }
    dst[idx] = v;
}

// ---------------------------------------------------------------------------
// Kernel 1: per-pair geometry -> rad[8], Y1[3], Y2[5], maskf  (fp32)
// ---------------------------------------------------------------------------
__global__ __launch_bounds__(256) void geom_kernel(
    const float* __restrict__ pos, const float* __restrict__ cell,
    float* __restrict__ rad, float* __restrict__ Y1, float* __restrict__ Y2,
    float* __restrict__ maskf)
{
    int p = blockIdx.x * 256 + threadIdx.x;
    if (p >= NPAIR) return;
    int b = p >> 12;
    int ij = p & 4095;
    int i = ij >> 6, j = ij & 63;
    const float* pi = pos + (size_t)(b*N_ + i)*3;
    const float* pj = pos + (size_t)(b*N_ + j)*3;
    float d0 = pi[0]-pj[0], d1 = pi[1]-pj[1], d2 = pi[2]-pj[2];
    d0 -= rintf(d0); d1 -= rintf(d1); d2 -= rintf(d2);
    const float* C = cell + b*9;
    float dc0 = d0*C[0] + d1*C[3] + d2*C[6];
    float dc1 = d0*C[1] + d1*C[4] + d2*C[7];
    float dc2 = d0*C[2] + d1*C[5] + d2*C[8];
    float r2 = fmaxf(dc0*dc0 + dc1*dc1 + dc2*dc2, 1e-12f);
    float r = sqrtf(r2);
    bool m = (r < 5.0f) && (i != j);
    float mf = m ? 1.0f : 0.0f;
    float rs = m ? r : 1.0f;
    float inv_rs = 1.0f / rs;
    float x = dc0*inv_rs*mf, y = dc1*inv_rs*mf, z = dc2*inv_rs*mf;
    float u = r * 0.2f;
    float u2 = u*u, u4 = u2*u2, u5 = u4*u;
    float fc = 1.0f - 21.0f*u5 + 35.0f*u5*u - 15.0f*u5*u2;
    fc = (u < 1.0f) ? fc : 0.0f;
    float pref = 0.6324555320336759f * inv_rs * (fc * mf);
    float w = 0.6283185307179586f * rs;
    float sw = sinf(w), cw = cosf(w);
    float twoc = 2.0f * cw;
    float sm = 0.0f, s = sw;
    #pragma unroll
    for (int n = 1; n <= 8; n++) {
        rad[(size_t)p*8 + (n-1)] = pref * s;
        float nx = twoc*s - sm;
        sm = s; s = nx;
    }
    const float s3  = 1.7320508075688772f;
    const float s5  = 2.23606797749979f;
    const float s15 = 3.872983346207417f;
    float* y1 = Y1 + (size_t)p*3;
    y1[0] = s3*x; y1[1] = s3*y; y1[2] = s3*z;
    float* y2 = Y2 + (size_t)p*5;
    y2[0] = s15*x*y;
    y2[1] = s15*y*z;
    y2[2] = 0.5f*s5*(3.0f*z*z - 1.0f);
    y2[3] = s15*x*z;
    y2[4] = 0.5f*s15*(x*x - y*y);
    maskf[p] = mf;
}

// ---------------------------------------------------------------------------
// 2-row-tile MFMA MLP layer (2 nodes/block variant): wave u of a node owns
// row-tiles {2u, 2u+1}. B-fragment loaded once, shared by both row-tiles.
// TR=1 writes transposed dstT[col][row].
// ---------------------------------------------------------------------------
template<int TR>
__device__ __forceinline__ void mfma_layer2(
    const short* __restrict__ src, const short* __restrict__ WT,
    const float* __restrict__ bias, short* __restrict__ dst,
    int u, int qd, int nn)
{
    floatx4 acc[2][4];
    #pragma unroll
    for (int r = 0; r < 2; r++)
        #pragma unroll
        for (int tt = 0; tt < 4; tt++) acc[r][tt] = (floatx4){0.f, 0.f, 0.f, 0.f};
    #pragma unroll
    for (int ks = 0; ks < 64; ks += 32) {
        bf16x8 a0 = ld_frag(&src[((u*2+0)*16 + nn)*72 + ks + qd*8]);
        bf16x8 a1 = ld_frag(&src[((u*2+1)*16 + nn)*72 + ks + qd*8]);
        #pragma unroll
        for (int tt = 0; tt < 4; tt++) {
            bf16x8 b = ld_frag(&WT[(tt*16 + nn)*64 + ks + qd*8]);
            acc[0][tt] = __builtin_amdgcn_mfma_f32_16x16x32_bf16(a0, b, acc[0][tt], 0, 0, 0);
            acc[1][tt] = __builtin_amdgcn_mfma_f32_16x16x32_bf16(a1, b, acc[1][tt], 0, 0, 0);
        }
    }
    #pragma unroll
    for (int r = 0; r < 2; r++)
        #pragma unroll
        for (int tt = 0; tt < 4; tt++) {
            int col = tt*16 + nn;
            float bv = bias[col];
            #pragma unroll
            for (int i = 0; i < 4; i++) {
                int row = (u*2+r)*16 + qd*4 + i;
                float v = silu_f(acc[r][tt][i] + bv);
                if (TR) dst[col*72 + row] = f2bf(v);
                else    dst[row*72 + col] = f2bf(v);
            }
        }
}

// L0 (K=32): rad_bf[64][32] @ w0T[64][32], 2 row-tiles per wave.
__device__ __forceinline__ void mfma_layer0_2(
    const short* __restrict__ rad_bf, const short* __restrict__ w0T,
    const float* __restrict__ b0, short* __restrict__ dst,
    int u, int qd, int nn)
{
    floatx4 acc[2][4];
    #pragma unroll
    for (int r = 0; r < 2; r++)
        #pragma unroll
        for (int tt = 0; tt < 4; tt++) acc[r][tt] = (floatx4){0.f, 0.f, 0.f, 0.f};
    bf16x8 a0 = ld_frag(&rad_bf[((u*2+0)*16 + nn)*32 + qd*8]);
    bf16x8 a1 = ld_frag(&rad_bf[((u*2+1)*16 + nn)*32 + qd*8]);
    #pragma unroll
    for (int tt = 0; tt < 4; tt++) {
        bf16x8 b = ld_frag(&w0T[(tt*16 + nn)*32 + qd*8]);
        acc[0][tt] = __builtin_amdgcn_mfma_f32_16x16x32_bf16(a0, b, acc[0][tt], 0, 0, 0);
        acc[1][tt] = __builtin_amdgcn_mfma_f32_16x16x32_bf16(a1, b, acc[1][tt], 0, 0, 0);
    }
    #pragma unroll
    for (int r = 0; r < 2; r++)
        #pragma unroll
        for (int tt = 0; tt < 4; tt++) {
            int col = tt*16 + nn;
            float bv = b0[col];
            #pragma unroll
            for (int i = 0; i < 4; i++) {
                int row = (u*2+r)*16 + qd*4 + i;
                dst[row*72 + col] = f2bf(silu_f(acc[r][tt][i] + bv));
            }
        }
}

// ---------------------------------------------------------------------------
// Kernel 2 (pass 1): TWO nodes per block. Waves {0,1}->node 0, {2,3}->node 1.
// Per-node LDS region (23040 B, x2 = 46080 B -> 3 blocks/CU):
//   R0 [0..9216):      actA / (late) A2 [16][136] bf16
//   R1 [9216..18432):  actB / (late) msg2 [5][128] f32 / Psa|Psb
//   R2 [18432..23040): rad_bf [64][32] / (after L0) Ym_bf [16][72] (+SY pads)
//                      + G_bf [16][72] at +2304
// ---------------------------------------------------------------------------
__global__ __launch_bounds__(256) void pass1_kernel(
    const float* __restrict__ rad, const float* __restrict__ Y1g,
    const float* __restrict__ Y2g, const float* __restrict__ maskg,
    const float* __restrict__ wemb,
    const short* __restrict__ w0T, const float* __restrict__ b0,
    const short* __restrict__ w1T, const float* __restrict__ b1,
    const short* __restrict__ w2T, const float* __restrict__ b2,
    const short* __restrict__ w3T, const float* __restrict__ b3,
    const short* __restrict__ lcatT, const float* __restrict__ timeg,
    float* __restrict__ h1g, float* __restrict__ v1g, short* __restrict__ featsb)
{
    __shared__ __align__(16) char smem[46080];
    int t = threadIdx.x;
    int wv = t >> 6, lane = t & 63, qd = lane >> 4, nn = lane & 15;
    int ln = wv >> 1;          // local node
    int u  = wv & 1;           // wave within node
    int tl = t & 127;          // thread within node group
    int node = blockIdx.x*2 + ln;
    int b = node >> 6;
    size_t pbase = (size_t)node * 64;

    char* base = smem + ln*23040;
    short* actA   = (short*)base;                   // [64][72]
    short* actB   = (short*)(base + 9216);          // [64][72]
    float* msg2f  = (float*)(base + 9216);          // alias actB: [5][128] (m=4..8)
    short* rad_bf = (short*)(base + 18432);         // [64][32]
    short* Ym_bf  = (short*)(base + 18432);         // alias: [16][72], SY in col-64 pads
    short* G_bf   = (short*)(base + 18432 + 2304);  // [16][72]
    short* A2     = (short*)base;                   // alias actA: [16][136]
    float* Psa    = (float*)(base + 9216);          // alias msg2f
    float* Psb    = Psa + 128;

    // ---- stage 1: rad -> bf16 [64][32]; tl<64 preload Y/mask + SY reduce ----
    for (int idx = tl; idx < 2048; idx += 128) {
        int j = idx >> 5, k = idx & 31;
        rad_bf[j*32 + k] = (k < 8) ? f2bf(rad[pbase*8 + j*8 + k]) : (short)0;
    }
    float vals[9];
    float sy9[9];
    if (tl < 64) {
        int j = tl;
        float mf = maskg[pbase + j];
        vals[0] = mf;
        #pragma unroll
        for (int m = 0; m < 3; m++) vals[1+m] = Y1g[(pbase+j)*3 + m] * mf;
        #pragma unroll
        for (int m = 0; m < 5; m++) vals[4+m] = Y2g[(pbase+j)*5 + m] * mf;
        #pragma unroll
        for (int m = 0; m < 9; m++) {
            float s = vals[m];
            #pragma unroll
            for (int off = 32; off > 0; off >>= 1) s += __shfl_xor(s, off);
            sy9[m] = s;
        }
    }
    __syncthreads();

    // ---- stage 2: L0 ----
    mfma_layer0_2(rad_bf, w0T, b0, actA, u, qd, nn);
    __syncthreads();

    // ---- stage 3: write Ym/SY (rad dead); L1 ----
    if (tl < 64) {
        int j = tl;
        #pragma unroll
        for (int m = 0; m < 9; m++) Ym_bf[m*72 + j] = f2bf(vals[m]);
        #pragma unroll
        for (int m = 9; m < 16; m++) Ym_bf[m*72 + j] = 0;
        #pragma unroll
        for (int m = 0; m < 9; m++)
            if (j == m) *(float*)(&Ym_bf[m*72 + 64]) = sy9[m];
    }
    mfma_layer2<0>(actA, w1T, b1, actB, u, qd, nn);
    __syncthreads();

    // ---- stage 4: L2 transposed (actB -> actA = hcT[h][j]) ----
    mfma_layer2<1>(actB, w2T, b2, actA, u, qd, nn);
    __syncthreads();

    // ---- stage 5: G[m][h]; wave u owns h-tiles {2u,2u+1} ----
    {
        bf16x8 ya0 = ld_frag(&Ym_bf[nn*72 + qd*8]);
        bf16x8 ya1 = ld_frag(&Ym_bf[nn*72 + 32 + qd*8]);
        #pragma unroll
        for (int hh = 0; hh < 2; hh++) {
            int ht = u*2 + hh;
            floatx4 acc = (floatx4){0.f, 0.f, 0.f, 0.f};
            bf16x8 b0f = ld_frag(&actA[(ht*16 + nn)*72 + qd*8]);
            bf16x8 b1f = ld_frag(&actA[(ht*16 + nn)*72 + 32 + qd*8]);
            acc = __builtin_amdgcn_mfma_f32_16x16x32_bf16(ya0, b0f, acc, 0, 0, 0);
            acc = __builtin_amdgcn_mfma_f32_16x16x32_bf16(ya1, b1f, acc, 0, 0, 0);
            #pragma unroll
            for (int i = 0; i < 4; i++)
                G_bf[(qd*4 + i)*72 + ht*16 + nn] = f2bf(acc[i]);
        }
    }
    __syncthreads();

    // ---- stage 6: T = G@w3T (24 tiles/node, 12/wave in 2 groups).
    //      Scatter: m=0 -> A2 row0; m=1..3 -> A2 rows 2..4; m=4..8 -> msg2f ----
    {
        bf16x8 ga0 = ld_frag(&G_bf[nn*72 + qd*8]);
        bf16x8 ga1 = ld_frag(&G_bf[nn*72 + 32 + qd*8]);
        #pragma unroll
        for (int g2 = 0; g2 < 2; g2++) {
            floatx4 acc[6];
            #pragma unroll
            for (int tt = 0; tt < 6; tt++) acc[tt] = (floatx4){0.f, 0.f, 0.f, 0.f};
            #pragma unroll
            for (int tt = 0; tt < 6; tt++) {
                int tn = u*12 + g2*6 + tt;
                bf16x8 b0f = ld_frag(&w3T[(tn*16 + nn)*64 + qd*8]);
                bf16x8 b1f = ld_frag(&w3T[(tn*16 + nn)*64 + 32 + qd*8]);
                acc[tt] = __builtin_amdgcn_mfma_f32_16x16x32_bf16(ga0, b0f, acc[tt], 0, 0, 0);
                acc[tt] = __builtin_amdgcn_mfma_f32_16x16x32_bf16(ga1, b1f, acc[tt], 0, 0, 0);
            }
            #pragma unroll
            for (int tt = 0; tt < 6; tt++) {
                int col = (u*12 + g2*6 + tt)*16 + nn;
                #pragma unroll
                for (int i = 0; i < 4; i++) {
                    int m = qd*4 + i;
                    if (m < 9) {
                        int c = (m == 0) ? 0 : ((m < 4) ? 1 : 2);
                        int k = col - c*128;
                        if (k >= 0 && k < 128) {
                            float sym = *(const float*)(&Ym_bf[m*72 + 64]);
                            float val = (acc[tt][i] + sym*b3[col]) * wemb[k] * 0.0625f;
                            if (m == 0)      A2[k] = f2bf(val);
                            else if (m < 4)  A2[(m+1)*136 + k] = f2bf(val);
                            else             msg2f[(m-4)*128 + k] = val;
                        }
                    }
                }
            }
        }
    }
    __syncthreads();

    // ---- stage 7: q -> A2 row1; zero A2 rows 5..15 ----
    if (tl < 128) {
        int k = tl;
        float acc = 0.f;
        #pragma unroll
        for (int m = 0; m < 5; m++) { float v = msg2f[m*128 + k]; acc += v*v; }
        A2[136 + k] = f2bf(acc);
    }
    for (int z = tl; z < 1408; z += 128) {
        int r = 5 + (z >> 7), k = z & 127;
        A2[r*136 + k] = 0;
    }
    __syncthreads();

    // ---- stage 9: P = A2 @ lcatT (24 tiles/node, 12/wave); extract ----
    {
        bf16x8 pa[4];
        #pragma unroll
        for (int ksI = 0; ksI < 4; ksI++)
            pa[ksI] = ld_frag(&A2[nn*136 + ksI*32 + qd*8]);
        #pragma unroll
        for (int g2 = 0; g2 < 2; g2++) {
            floatx4 acc[6];
            #pragma unroll
            for (int tt = 0; tt < 6; tt++) acc[tt] = (floatx4){0.f, 0.f, 0.f, 0.f};
            #pragma unroll
            for (int tt = 0; tt < 6; tt++) {
                int tn = u*12 + g2*6 + tt;
                #pragma unroll
                for (int ksI = 0; ksI < 4; ksI++) {
                    bf16x8 bf = ld_frag(&lcatT[((size_t)(tn*16 + nn))*128 + ksI*32 + qd*8]);
                    acc[tt] = __builtin_amdgcn_mfma_f32_16x16x32_bf16(pa[ksI], bf, acc[tt], 0, 0, 0);
                }
            }
            #pragma unroll
            for (int tt = 0; tt < 6; tt++) {
                int n = (u*12 + g2*6 + tt)*16 + nn;
                #pragma unroll
                for (int i = 0; i < 4; i++) {
                    int r = qd*4 + i;
                    float val = acc[tt][i];
                    if (r == 0 && n < 128) Psa[n] = val;
                    else if (r == 1 && n >= 256) Psb[n - 256] = val;
                    else if (r >= 2 && r < 5 && n >= 128 && n < 256) {
                        int m = r - 2, cc = n - 128;
                        v1g[(size_t)node*384 + m*128 + cc] = val;
                        featsb[(size_t)node*704 + 128 + m*128 + cc] = f2bf(val);
                    }
                }
            }
        }
    }
    __syncthreads();

    // ---- stage 10: finalize s1/h1/time/pad ----
    if (tl < 128) {
        float s1 = Psa[tl] + Psb[tl];
        featsb[(size_t)node*704 + tl] = f2bf(s1);
        h1g[(size_t)node*128 + tl] = silu_f(s1);
    }
    if (tl >= 64 && tl < 128) {
        int c = 640 + (tl - 64);
        featsb[(size_t)node*704 + c] = (tl == 64) ? f2bf(timeg[b]) : (short)0;
    }
}

// ---------------------------------------------------------------------------
// Kernel 3 (pass 2): TWO nodes per block. Per-node LDS 22528 B (x2 = 45056).
// ---------------------------------------------------------------------------
__global__ __launch_bounds__(256) void pass2_kernel(
    const float* __restrict__ rad, const float* __restrict__ Y1g,
    const float* __restrict__ maskg,
    const short* __restrict__ w0T, const float* __restrict__ b0,
    const short* __restrict__ w1T, const float* __restrict__ b1,
    const short* __restrict__ w2T, const float* __restrict__ b2,
    const short* __restrict__ w3T, const float* __restrict__ b3,
    const float* __restrict__ mix2,
    const float* __restrict__ h1g, const float* __restrict__ v1g,
    short* __restrict__ featsb)
{
    __shared__ __align__(16) char smem[45056];
    int t = threadIdx.x;
    int wv = t >> 6, lane = t & 63, qd = lane >> 4, nn = lane & 15;
    int ln = wv >> 1, u = wv & 1, tl = t & 127;
    int node = blockIdx.x*2 + ln;
    int b = node >> 6;
    size_t pbase = (size_t)node * 64;

    char* base = smem + ln*22528;
    short* actA   = (short*)base;                 // [64][72]
    short* actB   = (short*)(base + 9216);        // [64][72]
    short* rad_bf = (short*)(base + 18432);       // [64][32]
    float* aux    = (float*)(base + 18432);       // alias after L0
    float* mask_s = aux;          // [64]
    float* Y1s    = aux + 64;     // [64][4]
    float* msgab  = aux + 320;    // [128]

    // ---- stage 1: rad staging; preload mask/Y1 into regs ----
    for (int idx = tl; idx < 2048; idx += 128) {
        int j = idx >> 5, k = idx & 31;
        rad_bf[j*32 + k] = (k < 8) ? f2bf(rad[pbase*8 + j*8 + k]) : (short)0;
    }
    float pmf = 0.f, py0 = 0.f, py1 = 0.f, py2 = 0.f;
    if (tl < 64) {
        pmf = maskg[pbase + tl];
        py0 = Y1g[(pbase+tl)*3 + 0];
        py1 = Y1g[(pbase+tl)*3 + 1];
        py2 = Y1g[(pbase+tl)*3 + 2];
    }
    __syncthreads();

    // ---- stage 2: L0 ----
    mfma_layer0_2(rad_bf, w0T, b0, actA, u, qd, nn);
    __syncthreads();

    // ---- stage 3: write aux (rad dead); L1 ----
    if (tl < 64) {
        mask_s[tl] = pmf;
        Y1s[tl*4 + 0] = py0; Y1s[tl*4 + 1] = py1; Y1s[tl*4 + 2] = py2;
    }
    if (tl < 128) { if (tl < 128) msgab[tl & 127] = 0.f; }
    mfma_layer2<0>(actA, w1T, b1, actB, u, qd, nn);
    __syncthreads();

    // ---- stage 4: L2 (actB -> actA = hc) ----
    mfma_layer2<0>(actB, w2T, b2, actA, u, qd, nn);
    __syncthreads();

    // ---- stage 5: we2 = hc @ w3 [64x256]; wave u owns row-tiles {2u,2u+1};
    //      combine with h1/inv; accumulate msgab ----
    {
        bf16x8 af[2][2];
        #pragma unroll
        for (int r = 0; r < 2; r++) {
            int rt = u*2 + r;
            af[r][0] = ld_frag(&actA[(rt*16 + nn)*72 + qd*8]);
            af[r][1] = ld_frag(&actA[(rt*16 + nn)*72 + 32 + qd*8]);
        }
        for (int cg = 0; cg < 4; cg++) {
            floatx4 acc[2][4];
            #pragma unroll
            for (int r = 0; r < 2; r++)
                #pragma unroll
                for (int tt = 0; tt < 4; tt++) acc[r][tt] = (floatx4){0.f, 0.f, 0.f, 0.f};
            #pragma unroll
            for (int tt = 0; tt < 4; tt++) {
                int ct = cg*4 + tt;
                bf16x8 b0f = ld_frag(&w3T[(ct*16 + nn)*64 + qd*8]);
                bf16x8 b1f = ld_frag(&w3T[(ct*16 + nn)*64 + 32 + qd*8]);
                #pragma unroll
                for (int r = 0; r < 2; r++) {
                    acc[r][tt] = __builtin_amdgcn_mfma_f32_16x16x32_bf16(af[r][0], b0f, acc[r][tt], 0, 0, 0);
                    acc[r][tt] = __builtin_amdgcn_mfma_f32_16x16x32_bf16(af[r][1], b1f, acc[r][tt], 0, 0, 0);
                }
            }
            #pragma unroll
            for (int r = 0; r < 2; r++) {
                int rt = u*2 + r;
                #pragma unroll
                for (int tt = 0; tt < 4; tt++) {
                    int col = (cg*4 + tt)*16 + nn;
                    float bias = b3[col];
                    int k = col & 127;
                    float p = 0.f;
                    if (col < 128) {
                        #pragma unroll
                        for (int i = 0; i < 4; i++) {
                            int j = rt*16 + qd*4 + i;
                            float we = (acc[r][tt][i] + bias) * mask_s[j];
                            p += we * h1g[((size_t)b*64 + j)*128 + k];
                        }
                    } else {
                        #pragma unroll
                        for (int i = 0; i < 4; i++) {
                            int j = rt*16 + qd*4 + i;
                            float we = (acc[r][tt][i] + bias) * mask_s[j];
                            const float* vb = &v1g[((size_t)b*64 + j)*384 + k];
                            float inv = Y1s[j*4+0]*vb[0] + Y1s[j*4+1]*vb[128] + Y1s[j*4+2]*vb[256];
                            p += we * inv;
                        }
                    }
                    p += __shfl_xor(p, 16);
                    p += __shfl_xor(p, 32);
                    if (qd == 0) atomicAdd(&msgab[k], p);
                }
            }
        }
    }
    __syncthreads();

    // ---- stage 6: s2 = msgab @ mix2 / 16 ----
    if (tl < 128) {
        int c = tl;
        float acc = 0.f;
        for (int k = 0; k < 128; k++) acc += msgab[k] * mix2[k*128 + c];
        featsb[(size_t)node*704 + 512 + c] = f2bf(acc * 0.0625f);   // s2
    }
}

// ---------------------------------------------------------------------------
// Kernel 4: bf16 MFMA GEMM, C[M][ldo] = relu(A[M][lda] @ WT^T + bias), bf16 out.
// ---------------------------------------------------------------------------
__global__ __launch_bounds__(256) void gemm_mfma_kernel(
    const short* __restrict__ A, int lda,
    const short* __restrict__ BT, int ldb, int K,
    const float* __restrict__ bias, short* __restrict__ Cout, int ldo)
{
    __shared__ short As[64*72];
    __shared__ short Bs[64*72];
    int t = threadIdx.x;
    int wv = t >> 6, lane = t & 63, qd = lane >> 4, nn = lane & 15;
    int m0 = blockIdx.x * 64, n0 = blockIdx.y * 64;
    floatx4 acc[4];
    #pragma unroll
    for (int tt = 0; tt < 4; tt++) acc[tt] = (floatx4){0.f, 0.f, 0.f, 0.f};

    for (int kc = 0; kc < K; kc += 64) {
        for (int s = t; s < 512; s += 256) {
            int j = s >> 3, kk = (s & 7) * 8;
            *(uint4*)&As[j*72 + kk] = *(const uint4*)&A[(size_t)(m0 + j)*lda + kc + kk];
            *(uint4*)&Bs[j*72 + kk] = *(const uint4*)&BT[(size_t)(n0 + j)*ldb + kc + kk];
        }
        __syncthreads();
        #pragma unroll
        for (int ks = 0; ks < 64; ks += 32) {
            bf16x8 a = ld_frag(&As[(wv*16 + nn)*72 + ks + qd*8]);
            #pragma unroll
            for (int tt = 0; tt < 4; tt++) {
                bf16x8 bb = ld_frag(&Bs[(tt*16 + nn)*72 + ks + qd*8]);
                acc[tt] = __builtin_amdgcn_mfma_f32_16x16x32_bf16(a, bb, acc[tt], 0, 0, 0);
            }
        }
        __syncthreads();
    }
    #pragma unroll
    for (int tt = 0; tt < 4; tt++) {
        int n = n0 + tt*16 + nn;
        float bv = bias[n];
        #pragma unroll
        for (int i = 0; i < 4; i++) {
            int m = m0 + wv*16 + qd*4 + i;
            Cout[(size_t)m*ldo + n] = f2bf(fmaxf(acc[tt][i] + bv, 0.f));
        }
    }
}

// ---------------------------------------------------------------------------
// Kernel 5: out[node,3] = H(bf16)[node,512] @ w2[512,3] + b2. One wave/node.
// ---------------------------------------------------------------------------
__global__ __launch_bounds__(64) void final3_kernel(
    const short* __restrict__ H, const float* __restrict__ w2,
    const float* __restrict__ b2, float* __restrict__ out)
{
    int node = blockIdx.x, lane = threadIdx.x;
    float a0 = 0.f, a1 = 0.f, a2 = 0.f;
    #pragma unroll
    for (int r = 0; r < 8; r++) {
        int k = r*64 + lane;
        float h = bf2f(H[(size_t)node*512 + k]);
        a0 += h * w2[k*3 + 0];
        a1 += h * w2[k*3 + 1];
        a2 += h * w2[k*3 + 2];
    }
    #pragma unroll
    for (int off = 32; off > 0; off >>= 1) {
        a0 += __shfl_down(a0, off);
        a1 += __shfl_down(a1, off);
        a2 += __shfl_down(a2, off);
    }
    if (lane == 0) {
        out[(size_t)node*3 + 0] = a0 + b2[0];
        out[(size_t)node*3 + 1] = a1 + b2[1];
        out[(size_t)node*3 + 2] = a2 + b2[2];
    }
}

extern "C" void kernel_launch(void* const* d_in, const int* in_sizes, int n_in,
                              void* d_out, int out_size, void* d_ws, size_t ws_size,
                              hipStream_t stream) {
    const float* pos   = (const float*)d_in[0];
    const float* timeg = (const float*)d_in[1];
    const float* cell  = (const float*)d_in[2];
    const float* wemb  = (const float*)d_in[3];
    const float* r1w0  = (const float*)d_in[4];
    const float* r1b0  = (const float*)d_in[5];
    const float* r1w1  = (const float*)d_in[6];
    const float* r1b1  = (const float*)d_in[7];
    const float* r1w2  = (const float*)d_in[8];
    const float* r1b2  = (const float*)d_in[9];
    const float* r1w3  = (const float*)d_in[10];
    const float* r1b3  = (const float*)d_in[11];
    const float* l0    = (const float*)d_in[12];
    const float* l1    = (const float*)d_in[13];
    const float* l2    = (const float*)d_in[14];
    const float* r2w0  = (const float*)d_in[15];
    const float* r2b0  = (const float*)d_in[16];
    const float* r2w1  = (const float*)d_in[17];
    const float* r2b1  = (const float*)d_in[18];
    const float* r2w2  = (const float*)d_in[19];
    const float* r2b2  = (const float*)d_in[20];
    const float* r2w3  = (const float*)d_in[21];
    const float* r2b3  = (const float*)d_in[22];
    const float* mix2  = (const float*)d_in[23];
    const float* mw0   = (const float*)d_in[24];
    const float* mb0   = (const float*)d_in[25];
    const float* mw1   = (const float*)d_in[26];
    const float* mb1   = (const float*)d_in[27];
    const float* mw2   = (const float*)d_in[28];
    const float* mb2   = (const float*)d_in[29];

    float* ws    = (float*)d_ws;
    float* rad   = ws;                                   // 1,048,576 f
    float* Y1    = rad   + (size_t)NPAIR*8;              //   393,216 f
    float* Y2    = Y1    + (size_t)NPAIR*3;              //   655,360 f
    float* maskf = Y2    + (size_t)NPAIR*5;              //   131,072 f
    float* h1    = maskf + (size_t)NPAIR;                //   262,144 f
    float* v1    = h1    + (size_t)B_*N_*K_;             //   786,432 f
    short* featsb = (short*)(v1 + (size_t)B_*N_*3*K_);   // 1,441,792 sh (2048x704)
    short* prep  = featsb + (size_t)2048*704;            //   733,184 sh
    short* w1T_1 = prep;
    short* w2T_1 = prep + 4096;
    short* w1T_2 = prep + 8192;
    short* w2T_2 = prep + 12288;
    short* w3T_2 = prep + 16384;
    short* wT0   = prep + 32768;     // [512][704]
    short* wT1   = prep + 393216;    // [512][512]
    short* w0T_1 = prep + 655360;    // [64][32]
    short* w0T_2 = prep + 657408;    // [64][32]
    short* w3T_1 = prep + 659456;    // [384][64]
    short* lcatT = prep + 684032;    // [384][128]
    // final-MLP activations alias dead geometry buffers (sequenced after pass2):
    short* h0bb = (short*)rad;       // 2048x512 bf16 = 2 MB <= rad (4 MB)
    short* h1bb = (short*)Y2;        // 2048x512 bf16 = 2 MB <= Y2 (2.6 MB)

    prep_kernel<<<(PREP_TOTAL + 255)/256, 256, 0, stream>>>(
        r1w1, r1w2, r2w1, r2w2, r2w3, mw0, mw1,
        r1w0, r2w0, r1w3, l0, l1, l2, prep);
    geom_kernel<<<NPAIR/256, 256, 0, stream>>>(pos, cell, rad, Y1, Y2, maskf);
    pass1_kernel<<<B_*N_/2, 256, 0, stream>>>(rad, Y1, Y2, maskf, wemb,
        w0T_1, r1b0, w1T_1, r1b1, w2T_1, r1b2, w3T_1, r1b3, lcatT, timeg,
        h1, v1, featsb);
    pass2_kernel<<<B_*N_/2, 256, 0, stream>>>(rad, Y1, maskf,
        w0T_2, r2b0, w1T_2, r2b1, w2T_2, r2b2, w3T_2, r2b3, mix2, h1, v1, featsb);
    dim3 g0(32, 8);
    gemm_mfma_kernel<<<g0, 256, 0, stream>>>(featsb, 704, wT0, 704, 704, mb0, h0bb, 512);
    gemm_mfma_kernel<<<g0, 256, 0, stream>>>(h0bb, 512, wT1, 512, 512, mb1, h1bb, 512);
    final3_kernel<<<B_*N_, 64, 0, stream>>>(h1bb, mw2, mb2, (float*)d_out);
}